// Round 1
// baseline (1685.173 us; speedup 1.0000x reference)
//
#include <hip/hip_runtime.h>
#include <hip/hip_bf16.h>

// ---------------------------------------------------------------------------
// RRN: e' = l2norm(tanh([e;mem] Wc + bc));  per triple t (unique rows):
//   pair = [e'[s]; e'[o]];  out = tanh(pair @ Wr[l_t] + br[l_t])
//   e'[s] = l2norm(out[:128]); e'[o] = l2norm(out[128:]);  x2 iterations.
// All indices (subj ∪ obj) are distinct -> in-place update of e is race-free.
// ---------------------------------------------------------------------------

#define NROWS 200000
#define DD    128
#define KK    64
#define CINN  192
#define TT    50000
#define LL    8
#define BT    16
#define PADT  (TT + LL*BT)   // 50128, multiple of BT

// ws layout (bytes)
#define WS_COUNTS 0
#define WS_OFFS   64
#define WS_CURS   128
#define WS_BINS   256
#define WS_WR16   (256 + PADT*4)   // 200768, 16B aligned

typedef unsigned short u16;
typedef unsigned int   u32;

__device__ __forceinline__ void unpack2(u32 u, float& lo, float& hi){
  union { u32 x; float f; } a, b;
  a.x = u << 16;            // low bf16 -> f32
  b.x = u & 0xffff0000u;    // high bf16 -> f32
  lo = a.f; hi = b.f;
}
__device__ __forceinline__ u16 f2bf(float f){
  __hip_bfloat16 h = __float2bfloat16(f);
  return *reinterpret_cast<u16*>(&h);
}

// --- prep: Wr f32 -> bf16 in ws ---------------------------------------------
__global__ void k_conv_wr(const float* __restrict__ wr, u16* __restrict__ wr16, int n){
  int stride = gridDim.x * blockDim.x;
  for (int i = blockIdx.x*blockDim.x + threadIdx.x; i < n; i += stride)
    wr16[i] = f2bf(wr[i]);
}

// --- binning by layer --------------------------------------------------------
__global__ void k_hist(const int* __restrict__ layer, int* counts){
  int t = blockIdx.x*blockDim.x + threadIdx.x;
  if (t < TT) atomicAdd(&counts[layer[t]], 1);
}
__global__ void k_scan(const int* __restrict__ counts, int* offs, int* curs){
  if (threadIdx.x == 0 && blockIdx.x == 0){
    int acc = 0;
    for (int l = 0; l < LL; ++l){
      offs[l] = acc; curs[l] = acc;
      acc += ((counts[l] + BT - 1)/BT)*BT;   // pad each bin to BT
    }
    offs[LL] = acc;
  }
}
__global__ void k_scatter(const int* __restrict__ layer, int* curs, int* bins){
  int t = blockIdx.x*blockDim.x + threadIdx.x;
  if (t < TT){
    int l = layer[t];
    int pos = atomicAdd(&curs[l], 1);
    bins[pos] = t;
  }
}

// --- class update: e = l2norm(tanh([e;mem] Wc + bc)), in place ---------------
// 256 thr = 4 waves; Wc f32 in LDS (96KB); 32 rows/block-pass, 8 rows/wave
// (weight read reused across 8 rows -> VALU-bound, not LDS-bound).
__global__ __launch_bounds__(256) void k_class(float* __restrict__ e,
    const int* __restrict__ mem, const float* __restrict__ Wc,
    const float* __restrict__ bc, int n)
{
  __shared__ float sWc[CINN*DD];   // 96 KB
  __shared__ float sX[32][CINN];   // 24 KB
  __shared__ float sBc[DD];

  const int tid = threadIdx.x;
  for (int i = tid; i < CINN*DD/4; i += 256)
    ((float4*)sWc)[i] = ((const float4*)Wc)[i];
  if (tid < DD) sBc[tid] = bc[tid];

  const int wid = tid >> 6, lane = tid & 63;
  const int r8 = tid >> 3, q8 = tid & 7;   // staging: 8 threads per row

  for (int base = blockIdx.x*32; base < n; base += gridDim.x*32){
    __syncthreads();   // staging done (1st pass) / prior compute reads done
    int row = base + r8;
    const int cE = q8*16;
    if (row < n){
      const float4* src = (const float4*)(e + (size_t)row*DD + cE);
      float4 a0 = src[0], a1 = src[1], a2 = src[2], a3 = src[3];
      *(float4*)&sX[r8][cE]      = a0;
      *(float4*)&sX[r8][cE + 4]  = a1;
      *(float4*)&sX[r8][cE + 8]  = a2;
      *(float4*)&sX[r8][cE + 12] = a3;
      const int4* ms = (const int4*)(mem + (size_t)row*KK + q8*8);
      int4 m0 = ms[0], m1 = ms[1];
      float* dx = &sX[r8][DD + q8*8];
      dx[0]=(float)m0.x; dx[1]=(float)m0.y; dx[2]=(float)m0.z; dx[3]=(float)m0.w;
      dx[4]=(float)m1.x; dx[5]=(float)m1.y; dx[6]=(float)m1.z; dx[7]=(float)m1.w;
    } else {
      #pragma unroll
      for (int k = 0; k < 16; ++k) sX[r8][cE + k] = 0.f;
      float* dx = &sX[r8][DD + q8*8];
      #pragma unroll
      for (int k = 0; k < 8; ++k) dx[k] = 0.f;
    }
    __syncthreads();

    float acc0[8], acc1[8];
    #pragma unroll
    for (int t = 0; t < 8; ++t){ acc0[t] = sBc[lane]; acc1[t] = sBc[lane+64]; }

    for (int c = 0; c < CINN; c += 4){
      float w0[4], w1[4];
      #pragma unroll
      for (int dc = 0; dc < 4; ++dc){
        w0[dc] = sWc[(c+dc)*DD + lane];
        w1[dc] = sWc[(c+dc)*DD + lane + 64];
      }
      #pragma unroll
      for (int t = 0; t < 8; ++t){
        float4 p = *(const float4*)&sX[wid*8 + t][c];   // broadcast read
        acc0[t] = fmaf(p.x, w0[0], acc0[t]); acc1[t] = fmaf(p.x, w1[0], acc1[t]);
        acc0[t] = fmaf(p.y, w0[1], acc0[t]); acc1[t] = fmaf(p.y, w1[1], acc1[t]);
        acc0[t] = fmaf(p.z, w0[2], acc0[t]); acc1[t] = fmaf(p.z, w1[2], acc1[t]);
        acc0[t] = fmaf(p.w, w0[3], acc0[t]); acc1[t] = fmaf(p.w, w1[3], acc1[t]);
      }
    }

    #pragma unroll
    for (int t = 0; t < 8; ++t){
      int row2 = base + wid*8 + t;     // uniform across the wave
      if (row2 >= n) continue;
      float t0 = tanhf(acc0[t]), t1 = tanhf(acc1[t]);
      float ss = t0*t0 + t1*t1;
      #pragma unroll
      for (int m = 32; m >= 1; m >>= 1) ss += __shfl_xor(ss, m, 64);
      float scale = 1.0f / fmaxf(sqrtf(ss), 1e-12f);
      e[(size_t)row2*DD + lane]      = t0*scale;
      e[(size_t)row2*DD + lane + 64] = t1*scale;
    }
  }
}

// --- relation update: 16 same-layer triples/block, Wr[l] bf16 in LDS ---------
// thread: cols 4j..4j+3 (j=tid&63), triples 4g..4g+3 (g=tid>>6). 16 f32 accs.
__global__ __launch_bounds__(256) void k_rel(float* __restrict__ e,
    const int* __restrict__ subj, const int* __restrict__ obj,
    const u16* __restrict__ wr16, const float* __restrict__ br,
    const int* __restrict__ offs, const int* __restrict__ bins)
{
  __shared__ u16   sWr[256*256];   // 128 KB (bf16)
  __shared__ u16   sP[BT][256];    // 8 KB   (bf16 pairs)
  __shared__ float sBr[256];
  __shared__ int   sSubj[BT], sObj[BT];

  const int tid  = threadIdx.x;
  const int base = blockIdx.x * BT;
  const int total = offs[LL];
  if (base >= total) return;
  int l = 0;
  while (l < LL-1 && base >= offs[l+1]) ++l;

  // stage Wr[l]
  const uint4* gw = (const uint4*)(wr16 + (size_t)l*65536);
  uint4* sw = (uint4*)sWr;
  for (int i = tid; i < 8192; i += 256) sw[i] = gw[i];
  sBr[tid & 255] = br[l*256 + (tid & 255)];

  // gather pairs (16 threads per triple, 16 bf16 elems each)
  const int ti = tid >> 4, q = tid & 15;
  int id = bins[base + ti];
  int rs = -1, ro = -1;
  if (id >= 0){ rs = subj[id]; ro = obj[id]; }
  if (q == 0){ sSubj[ti] = rs; sObj[ti] = ro; }
  const int c0 = q*16;
  if (id >= 0){
    const float* src = (c0 < DD) ? (e + (size_t)rs*DD + c0)
                                 : (e + (size_t)ro*DD + (c0 - DD));
    #pragma unroll
    for (int v = 0; v < 4; ++v){
      float4 a = ((const float4*)src)[v];
      sP[ti][c0 + 4*v + 0] = f2bf(a.x);
      sP[ti][c0 + 4*v + 1] = f2bf(a.y);
      sP[ti][c0 + 4*v + 2] = f2bf(a.z);
      sP[ti][c0 + 4*v + 3] = f2bf(a.w);
    }
  } else {
    #pragma unroll
    for (int k = 0; k < 16; ++k) sP[ti][c0 + k] = 0;
  }
  __syncthreads();

  const int j = tid & 63, g = tid >> 6;
  float acc[4][4];
  #pragma unroll
  for (int t = 0; t < 4; ++t)
    #pragma unroll
    for (int c = 0; c < 4; ++c) acc[t][c] = sBr[4*j + c];

  for (int cb = 0; cb < 256; cb += 4){
    float w[4][4];
    #pragma unroll
    for (int dc = 0; dc < 4; ++dc){
      uint2 wv = *(const uint2*)&sWr[(cb+dc)*256 + 4*j];
      unpack2(wv.x, w[dc][0], w[dc][1]);
      unpack2(wv.y, w[dc][2], w[dc][3]);
    }
    #pragma unroll
    for (int t = 0; t < 4; ++t){
      uint2 pv = *(const uint2*)&sP[4*g + t][cb];   // broadcast read
      float p0,p1,p2,p3;
      unpack2(pv.x, p0, p1); unpack2(pv.y, p2, p3);
      #pragma unroll
      for (int c = 0; c < 4; ++c){
        acc[t][c] = fmaf(p0, w[0][c], acc[t][c]);
        acc[t][c] = fmaf(p1, w[1][c], acc[t][c]);
        acc[t][c] = fmaf(p2, w[2][c], acc[t][c]);
        acc[t][c] = fmaf(p3, w[3][c], acc[t][c]);
      }
    }
  }

  #pragma unroll
  for (int t = 0; t < 4; ++t){
    const int tri = 4*g + t;
    float v0 = tanhf(acc[t][0]), v1 = tanhf(acc[t][1]);
    float v2 = tanhf(acc[t][2]), v3 = tanhf(acc[t][3]);
    float ss = v0*v0 + v1*v1 + v2*v2 + v3*v3;
    #pragma unroll
    for (int m = 16; m >= 1; m >>= 1) ss += __shfl_xor(ss, m, 32); // half-wave: s|o
    int row = (j < 32) ? sSubj[tri] : sObj[tri];
    if (row >= 0){
      float scale = 1.0f / fmaxf(sqrtf(ss), 1e-12f);
      int cc = (j < 32) ? 4*j : 4*j - DD;
      float4 ov; ov.x = v0*scale; ov.y = v1*scale; ov.z = v2*scale; ov.w = v3*scale;
      *(float4*)(e + (size_t)row*DD + cc) = ov;
    }
  }
}

extern "C" void kernel_launch(void* const* d_in, const int* in_sizes, int n_in,
                              void* d_out, int out_size, void* d_ws, size_t ws_size,
                              hipStream_t stream) {
  (void)in_sizes; (void)n_in; (void)out_size; (void)ws_size;
  const float* emb  = (const float*)d_in[0];
  const int*   mem  = (const int*)  d_in[1];
  const int*   subj = (const int*)  d_in[2];
  const int*   obj  = (const int*)  d_in[3];
  const int*   lay  = (const int*)  d_in[4];
  const float* Wc   = (const float*)d_in[5];
  const float* bc   = (const float*)d_in[6];
  const float* Wr   = (const float*)d_in[7];
  const float* br   = (const float*)d_in[8];

  float* e   = (float*)d_out;
  char*  wsb = (char*)d_ws;
  int* counts = (int*)(wsb + WS_COUNTS);
  int* offs   = (int*)(wsb + WS_OFFS);
  int* curs   = (int*)(wsb + WS_CURS);
  int* bins   = (int*)(wsb + WS_BINS);
  u16* wr16   = (u16*)(wsb + WS_WR16);

  hipMemcpyAsync(e, emb, (size_t)NROWS*DD*sizeof(float),
                 hipMemcpyDeviceToDevice, stream);
  hipMemsetAsync(wsb + WS_COUNTS, 0, 64, stream);
  hipMemsetAsync(wsb + WS_BINS, 0xFF, PADT*4, stream);   // bins = -1

  k_conv_wr<<<512, 256, 0, stream>>>(Wr, wr16, LL*256*256);
  k_hist   <<<(TT+255)/256, 256, 0, stream>>>(lay, counts);
  k_scan   <<<1, 64, 0, stream>>>(counts, offs, curs);
  k_scatter<<<(TT+255)/256, 256, 0, stream>>>(lay, curs, bins);

  for (int it = 0; it < 2; ++it){
    k_class<<<512, 256, 0, stream>>>(e, mem, Wc, bc, NROWS);
    k_rel  <<<PADT/BT, 256, 0, stream>>>(e, subj, obj, wr16, br, offs, bins);
  }
}

// Round 2
// 684.019 us; speedup vs baseline: 2.4636x; 2.4636x over previous
//
#include <hip/hip_runtime.h>
#include <hip/hip_bf16.h>

// ---------------------------------------------------------------------------
// RRN, MFMA version.
//   iter: e = l2norm(tanh([e;mem] @ Wc + bc))            (K=192 GEMM, MFMA)
//         per triple (unique rows): out = tanh([e_s;e_o] @ Wr[l] + br[l])
//         e[s]=l2norm(out[:128]); e[o]=l2norm(out[128:])  (layer-binned MFMA)
// subj ∪ obj are distinct rows -> in-place update race-free.
// ---------------------------------------------------------------------------

#define NROWS 200000
#define DD    128
#define KK    64
#define TT    50000
#define LL    8
#define BT    64
#define PADT  50560            // 64*790 >= 50000 + 8*63

// ws layout (bytes)
#define WS_COUNTS 0
#define WS_OFFS   64
#define WS_CURS   128
#define WS_BINS   256
#define WS_WCP    (256 + PADT*4)          // 202496, 16B aligned; 48 KB
#define WS_WRP    (WS_WCP + 6*8*64*16)    // 251648; 1 MB

typedef unsigned short u16;
typedef unsigned int   u32;
typedef __attribute__((ext_vector_type(8))) short bf16x8;
typedef __attribute__((ext_vector_type(4))) float f32x4;

#define SWZ(row, byte) ((byte) ^ (((row)&7)<<4))

__device__ __forceinline__ u32 bfbits(float f){
  __hip_bfloat16 h = __float2bfloat16(f);
  return (u32)*reinterpret_cast<unsigned short*>(&h);
}
__device__ __forceinline__ u32 pk(float lo, float hi){
  return bfbits(lo) | (bfbits(hi) << 16);
}
__device__ __forceinline__ float qreduce16(float ss){
  ss += __shfl_xor(ss, 1, 64);
  ss += __shfl_xor(ss, 2, 64);
  ss += __shfl_xor(ss, 4, 64);
  ss += __shfl_xor(ss, 8, 64);
  return ss;
}

// --- prep: pack Wc (192x128) and Wr (8x256x256) into MFMA B-fragment order --
// frag(kt,nt): lane l, slots e=0..7 -> W[kt*32 + (l>>4)*8 + e][nt*16 + (l&15)]
__global__ void k_prep(const float* __restrict__ Wc, const float* __restrict__ Wr,
                       uint4* __restrict__ wcp, uint4* __restrict__ wrp)
{
  int id = blockIdx.x*blockDim.x + threadIdx.x;
  if (id < 3072){                       // wcp: kt 0..5, nt 0..7
    int lane = id & 63, nt = (id >> 6) & 7, kt = id >> 9;
    int k0 = kt*32 + (lane>>4)*8, n = nt*16 + (lane&15);
    u32 p[4];
    #pragma unroll
    for (int e2 = 0; e2 < 4; ++e2)
      p[e2] = pk(Wc[(k0 + 2*e2)*DD + n], Wc[(k0 + 2*e2 + 1)*DD + n]);
    wcp[id] = make_uint4(p[0], p[1], p[2], p[3]);
  } else if (id < 3072 + 65536){        // wrp: l, kt 0..7, nt 0..15
    int id2 = id - 3072;
    int lane = id2 & 63, nt = (id2>>6) & 15, kt = (id2>>10) & 7, l = id2 >> 13;
    int k0 = kt*32 + (lane>>4)*8, n = nt*16 + (lane&15);
    const float* w = Wr + (size_t)l*65536;
    u32 p[4];
    #pragma unroll
    for (int e2 = 0; e2 < 4; ++e2)
      p[e2] = pk(w[(k0 + 2*e2)*256 + n], w[(k0 + 2*e2 + 1)*256 + n]);
    wrp[id2] = make_uint4(p[0], p[1], p[2], p[3]);
  }
}

// --- binning by layer --------------------------------------------------------
__global__ void k_hist(const int* __restrict__ layer, int* counts){
  int t = blockIdx.x*blockDim.x + threadIdx.x;
  if (t < TT) atomicAdd(&counts[layer[t]], 1);
}
__global__ void k_scan(const int* __restrict__ counts, int* offs, int* curs){
  if (threadIdx.x == 0 && blockIdx.x == 0){
    int acc = 0;
    for (int l = 0; l < LL; ++l){
      offs[l] = acc; curs[l] = acc;
      acc += ((counts[l] + BT - 1)/BT)*BT;
    }
    offs[LL] = acc;
  }
}
__global__ void k_scatter(const int* __restrict__ layer, int* curs, int* bins){
  int t = blockIdx.x*blockDim.x + threadIdx.x;
  if (t < TT){
    int pos = atomicAdd(&curs[layer[t]], 1);
    bins[pos] = t;
  }
}

// --- class update: dst = l2norm(tanh([src;mem] @ Wc + bc)) -------------------
// 64 rows/pass, 4 waves: wave w owns M-tile w (16 rows) x 8 nt x 6 kt MFMAs.
__global__ __launch_bounds__(256) void k_class(
    const float* __restrict__ src, float* __restrict__ dst,
    const int* __restrict__ mem, const uint4* __restrict__ wcp,
    const float* __restrict__ bc)
{
  __shared__ u16   sW[6*8*64*8];   // 48 KB packed B-frags
  __shared__ u16   sA[64*192];     // 24 KB, row stride 384 B, XOR-swizzled
  __shared__ float sBc[DD];

  const int tid = threadIdx.x;
  {
    uint4* sw = (uint4*)sW;
    for (int i = tid; i < 3072; i += 256) sw[i] = wcp[i];
    if (tid < DD) sBc[tid] = bc[tid];
  }
  const int lane = tid & 63, wid = tid >> 6;
  const int colj = lane & 15, qw = lane >> 4;

  for (int rb = blockIdx.x; rb < NROWS/64; rb += gridDim.x){
    const int rowbase = rb * 64;
    __syncthreads();   // W staged (1st) / prior pass frag reads done
    // stage e-part (64x128 f32 -> bf16), flat-coalesced
    #pragma unroll
    for (int v = 0; v < 4; ++v){
      int f = (v*256 + tid) * 8;               // flat f32 idx in 64x128
      int row = f >> 7, col = f & 127;
      const float4* s4 = (const float4*)(src + (size_t)(rowbase+row)*DD + col);
      float4 a = s4[0], b = s4[1];
      *(uint4*)((char*)sA + row*384 + SWZ(row, col*2)) =
        make_uint4(pk(a.x,a.y), pk(a.z,a.w), pk(b.x,b.y), pk(b.z,b.w));
    }
    // stage mem-part (64x64 int 0/1 -> bf16)
    #pragma unroll
    for (int v = 0; v < 2; ++v){
      int f = (v*256 + tid) * 8;               // flat int idx in 64x64
      int row = f >> 6, col = f & 63;
      const int4* s4 = (const int4*)(mem + (size_t)(rowbase+row)*KK + col);
      int4 a = s4[0], b = s4[1];
      u32 p0 = (a.x?0x3F80u:0u) | ((a.y?0x3F80u:0u)<<16);
      u32 p1 = (a.z?0x3F80u:0u) | ((a.w?0x3F80u:0u)<<16);
      u32 p2 = (b.x?0x3F80u:0u) | ((b.y?0x3F80u:0u)<<16);
      u32 p3 = (b.z?0x3F80u:0u) | ((b.w?0x3F80u:0u)<<16);
      *(uint4*)((char*)sA + row*384 + SWZ(row, 256 + col*2)) =
        make_uint4(p0, p1, p2, p3);
    }
    __syncthreads();

    bf16x8 afr[6];
    #pragma unroll
    for (int kt = 0; kt < 6; ++kt){
      int row = wid*16 + colj;
      afr[kt] = *(bf16x8*)((char*)sA + row*384 + SWZ(row, kt*64 + qw*16));
    }
    f32x4 acc[8];
    #pragma unroll
    for (int nt = 0; nt < 8; ++nt) acc[nt] = (f32x4){0.f,0.f,0.f,0.f};
    #pragma unroll
    for (int nt = 0; nt < 8; ++nt){
      #pragma unroll
      for (int kt = 0; kt < 6; ++kt){
        bf16x8 bfr = *(bf16x8*)&sW[((kt*8 + nt)*64 + lane)*8];
        acc[nt] = __builtin_amdgcn_mfma_f32_16x16x32_bf16(afr[kt], bfr, acc[nt], 0,0,0);
      }
    }
    // epilogue: tanh + row l2norm (row i lives in one 16-lane group, reg i&3)
    #pragma unroll
    for (int r = 0; r < 4; ++r){
      int grow = rowbase + wid*16 + qw*4 + r;
      float t[8], ss = 0.f;
      #pragma unroll
      for (int nt = 0; nt < 8; ++nt){
        t[nt] = tanhf(acc[nt][r] + sBc[nt*16 + colj]);
        ss += t[nt]*t[nt];
      }
      ss = qreduce16(ss);
      float sc = 1.0f / fmaxf(sqrtf(ss), 1e-12f);
      #pragma unroll
      for (int nt = 0; nt < 8; ++nt)
        dst[(size_t)grow*DD + nt*16 + colj] = t[nt]*sc;
    }
  }
}

// --- relation update: 64 same-layer triples/block; B-frags straight from L2 --
__global__ __launch_bounds__(256) void k_rel(
    float* __restrict__ e, const int* __restrict__ subj,
    const int* __restrict__ obj, const uint4* __restrict__ wrp,
    const float* __restrict__ br, const int* __restrict__ offs,
    const int* __restrict__ bins)
{
  __shared__ u16   sA[64*256];   // 32 KB pairs bf16, row stride 512 B, swizzled
  __shared__ float sBr[256];
  __shared__ int   sS[BT], sO[BT];

  const int tid  = threadIdx.x;
  const int base = blockIdx.x * BT;
  if (base >= offs[LL]) return;
  int l = 0;
  while (l < LL-1 && base >= offs[l+1]) ++l;

  sBr[tid] = br[l*256 + tid];

  // gather pairs: 4 threads per triple, 64 f32 each
  const int ti = tid >> 2, q = tid & 3;
  int id = bins[base + ti];
  int rs = -1, ro = -1;
  if (id >= 0){ rs = subj[id]; ro = obj[id]; }
  if (q == 0){ sS[ti] = rs; sO[ti] = ro; }
  const float* srcp = nullptr;
  if (id >= 0){
    int rr = (q < 2) ? rs : ro;
    srcp = e + (size_t)rr*DD + (q & 1)*64;
  }
  #pragma unroll
  for (int j = 0; j < 8; ++j){
    uint4 w;
    if (id >= 0){
      float4 a = ((const float4*)srcp)[2*j], b = ((const float4*)srcp)[2*j+1];
      w = make_uint4(pk(a.x,a.y), pk(a.z,a.w), pk(b.x,b.y), pk(b.z,b.w));
    } else w = make_uint4(0u,0u,0u,0u);
    *(uint4*)((char*)sA + ti*512 + SWZ(ti, q*128 + j*16)) = w;
  }
  __syncthreads();

  const int lane = tid & 63, wid = tid >> 6;
  const int colj = lane & 15, qw = lane >> 4;

  bf16x8 afr[8];
  #pragma unroll
  for (int kt = 0; kt < 8; ++kt){
    int row = wid*16 + colj;
    afr[kt] = *(bf16x8*)((char*)sA + row*512 + SWZ(row, kt*64 + qw*16));
  }
  const uint4* wb = wrp + (size_t)l*8192 + lane;
  f32x4 acc[16];
  #pragma unroll
  for (int nt = 0; nt < 16; ++nt) acc[nt] = (f32x4){0.f,0.f,0.f,0.f};
  #pragma unroll
  for (int nt = 0; nt < 16; ++nt){
    #pragma unroll
    for (int kt = 0; kt < 8; ++kt){
      bf16x8 bfr = *(const bf16x8*)&wb[(kt*16 + nt)*64];
      acc[nt] = __builtin_amdgcn_mfma_f32_16x16x32_bf16(afr[kt], bfr, acc[nt], 0,0,0);
    }
  }
  // epilogue: per row, subj half (nt 0..7) and obj half (nt 8..15)
  #pragma unroll
  for (int r = 0; r < 4; ++r){
    int tri = wid*16 + qw*4 + r;
    float t[8], ss = 0.f;
    #pragma unroll
    for (int nt = 0; nt < 8; ++nt){
      t[nt] = tanhf(acc[nt][r] + sBr[nt*16 + colj]);
      ss += t[nt]*t[nt];
    }
    ss = qreduce16(ss);
    int srow = sS[tri];
    if (srow >= 0){
      float sc = 1.0f / fmaxf(sqrtf(ss), 1e-12f);
      #pragma unroll
      for (int nt = 0; nt < 8; ++nt)
        e[(size_t)srow*DD + nt*16 + colj] = t[nt]*sc;
    }
    float u[8], ss2 = 0.f;
    #pragma unroll
    for (int nt = 0; nt < 8; ++nt){
      u[nt] = tanhf(acc[nt+8][r] + sBr[(nt+8)*16 + colj]);
      ss2 += u[nt]*u[nt];
    }
    ss2 = qreduce16(ss2);
    int orow = sO[tri];
    if (orow >= 0){
      float sc = 1.0f / fmaxf(sqrtf(ss2), 1e-12f);
      #pragma unroll
      for (int nt = 0; nt < 8; ++nt)
        e[(size_t)orow*DD + nt*16 + colj] = u[nt]*sc;
    }
  }
}

extern "C" void kernel_launch(void* const* d_in, const int* in_sizes, int n_in,
                              void* d_out, int out_size, void* d_ws, size_t ws_size,
                              hipStream_t stream) {
  (void)in_sizes; (void)n_in; (void)out_size; (void)ws_size;
  const float* emb  = (const float*)d_in[0];
  const int*   mem  = (const int*)  d_in[1];
  const int*   subj = (const int*)  d_in[2];
  const int*   obj  = (const int*)  d_in[3];
  const int*   lay  = (const int*)  d_in[4];
  const float* Wc   = (const float*)d_in[5];
  const float* bc   = (const float*)d_in[6];
  const float* Wr   = (const float*)d_in[7];
  const float* br   = (const float*)d_in[8];

  float* e   = (float*)d_out;
  char*  wsb = (char*)d_ws;
  int*   counts = (int*)(wsb + WS_COUNTS);
  int*   offs   = (int*)(wsb + WS_OFFS);
  int*   curs   = (int*)(wsb + WS_CURS);
  int*   bins   = (int*)(wsb + WS_BINS);
  uint4* wcp    = (uint4*)(wsb + WS_WCP);
  uint4* wrp    = (uint4*)(wsb + WS_WRP);

  hipMemsetAsync(wsb + WS_COUNTS, 0, 64, stream);
  hipMemsetAsync(wsb + WS_BINS, 0xFF, PADT*4, stream);

  k_prep   <<<268, 256, 0, stream>>>(Wc, Wr, wcp, wrp);
  k_hist   <<<(TT+255)/256, 256, 0, stream>>>(lay, counts);
  k_scan   <<<1, 64, 0, stream>>>(counts, offs, curs);
  k_scatter<<<(TT+255)/256, 256, 0, stream>>>(lay, curs, bins);

  // iter 0 reads emb directly (saves the 102 MB d2d copy)
  k_class<<<512, 256, 0, stream>>>(emb, e, mem, wcp, bc);
  k_rel  <<<PADT/BT, 256, 0, stream>>>(e, subj, obj, wrp, br, offs, bins);
  k_class<<<512, 256, 0, stream>>>(e, e, mem, wcp, bc);
  k_rel  <<<PADT/BT, 256, 0, stream>>>(e, subj, obj, wrp, br, offs, bins);
}

// Round 3
// 400.746 us; speedup vs baseline: 4.2051x; 1.7069x over previous
//
#include <hip/hip_runtime.h>
#include <hip/hip_bf16.h>

// ---------------------------------------------------------------------------
// RRN, MFMA version, scan-binned, bf16-resident e.
//   iter: e = l2norm(tanh([e;mem] @ Wc + bc))            (K=192 GEMM, MFMA)
//         per triple (unique rows): out = tanh([e_s;e_o] @ Wr[l] + br[l])
//         e[s]=l2norm(out[:128]); e[o]=l2norm(out[128:])  (layer-binned MFMA)
// subj ∪ obj are distinct rows -> in-place update race-free.
// e kept in bf16 (ws) between ops: MFMA consumers rounded to bf16 anyway, so
// this is bit-identical math with ~half the gather/stage traffic. Final iter
// writes f32 to d_out (class full-write, rel row-overwrite = last-write-wins).
// ---------------------------------------------------------------------------

#define NROWS 200000
#define DD    128
#define KK    64
#define TT    50000
#define LL    8
#define BT    64
#define PADT  50560            // 64*790 >= 50000 + 8*63

#define BINTH 1024
#define CH    ((TT + BINTH - 1)/BINTH)   // 49

// ws layout (bytes)
#define WS_OFFS   0
#define WS_BINS   64
#define WS_WCP    (64 + PADT*4)            // 202304 (16B aligned)
#define WS_WRP    (WS_WCP + 6*8*64*16)     // +48 KB
#define WS_E16    (WS_WRP + 8*8*16*64*16)  // +1 MB
#define WS_NEED   (WS_E16 + (size_t)NROWS*DD*2)

typedef unsigned short u16;
typedef unsigned int   u32;
typedef __attribute__((ext_vector_type(8))) short bf16x8;
typedef __attribute__((ext_vector_type(4))) float f32x4;

#define SWZ(row, byte) ((byte) ^ (((row)&7)<<4))

__device__ __forceinline__ u32 bfbits(float f){
  __hip_bfloat16 h = __float2bfloat16(f);
  return (u32)*reinterpret_cast<unsigned short*>(&h);
}
__device__ __forceinline__ u32 pk(float lo, float hi){
  return bfbits(lo) | (bfbits(hi) << 16);
}
__device__ __forceinline__ float qreduce16(float ss){
  ss += __shfl_xor(ss, 1, 64);
  ss += __shfl_xor(ss, 2, 64);
  ss += __shfl_xor(ss, 4, 64);
  ss += __shfl_xor(ss, 8, 64);
  return ss;
}

// --- prep: pack Wc (192x128) and Wr (8x256x256) into MFMA B-fragment order --
__global__ void k_prep(const float* __restrict__ Wc, const float* __restrict__ Wr,
                       uint4* __restrict__ wcp, uint4* __restrict__ wrp)
{
  int id = blockIdx.x*blockDim.x + threadIdx.x;
  if (id < 3072){                       // wcp: kt 0..5, nt 0..7
    int lane = id & 63, nt = (id >> 6) & 7, kt = id >> 9;
    int k0 = kt*32 + (lane>>4)*8, n = nt*16 + (lane&15);
    u32 p[4];
    #pragma unroll
    for (int e2 = 0; e2 < 4; ++e2)
      p[e2] = pk(Wc[(k0 + 2*e2)*DD + n], Wc[(k0 + 2*e2 + 1)*DD + n]);
    wcp[id] = make_uint4(p[0], p[1], p[2], p[3]);
  } else if (id < 3072 + 65536){        // wrp: l, kt 0..7, nt 0..15
    int id2 = id - 3072;
    int lane = id2 & 63, nt = (id2>>6) & 15, kt = (id2>>10) & 7, l = id2 >> 13;
    int k0 = kt*32 + (lane>>4)*8, n = nt*16 + (lane&15);
    const float* w = Wr + (size_t)l*65536;
    u32 p[4];
    #pragma unroll
    for (int e2 = 0; e2 < 4; ++e2)
      p[e2] = pk(w[(k0 + 2*e2)*256 + n], w[(k0 + 2*e2 + 1)*256 + n]);
    wrp[id2] = make_uint4(p[0], p[1], p[2], p[3]);
  }
}

// --- binning: one block, deterministic scan, NO atomics ---------------------
__global__ __launch_bounds__(BINTH) void k_bin(const int* __restrict__ layer,
                                               int* __restrict__ offs,
                                               int* __restrict__ bins)
{
  __shared__ int swtot[BINTH/64][LL];   // per-wave inclusive totals
  __shared__ int swpre[BINTH/64][LL];   // exclusive wave prefix
  __shared__ int sbase[LL];

  const int tid = threadIdx.x, lane = tid & 63, w = tid >> 6;
  const int i0 = tid * CH, i1 = (i0 + CH < TT) ? i0 + CH : TT;

  int c[LL] = {0,0,0,0,0,0,0,0};
  for (int i = i0; i < i1; ++i){
    int l = layer[i];
    #pragma unroll
    for (int k = 0; k < LL; ++k) c[k] += (l == k);
  }
  int inc[LL];
  #pragma unroll
  for (int k = 0; k < LL; ++k){
    int v = c[k];
    #pragma unroll
    for (int d = 1; d < 64; d <<= 1){
      int u = __shfl_up(v, d, 64);
      if (lane >= d) v += u;
    }
    inc[k] = v;
  }
  if (lane == 63){
    #pragma unroll
    for (int k = 0; k < LL; ++k) swtot[w][k] = inc[k];
  }
  __syncthreads();
  if (tid == 0){
    int acc = 0;
    for (int k = 0; k < LL; ++k){
      int tot = 0;
      for (int ww = 0; ww < BINTH/64; ++ww){ swpre[ww][k] = tot; tot += swtot[ww][k]; }
      sbase[k] = acc;
      offs[k] = acc;
      acc += ((tot + BT - 1)/BT)*BT;
    }
    offs[LL] = acc;
  }
  __syncthreads();
  int pos[LL];
  #pragma unroll
  for (int k = 0; k < LL; ++k)
    pos[k] = sbase[k] + swpre[w][k] + (inc[k] - c[k]);
  for (int i = i0; i < i1; ++i){
    int l = layer[i];
    #pragma unroll
    for (int k = 0; k < LL; ++k)
      if (l == k) bins[pos[k]++] = i;
  }
}

// --- class update: dst = l2norm(tanh([src;mem] @ Wc + bc)) -------------------
template<bool S16, bool W16, bool WF32>
__global__ __launch_bounds__(256) void k_class(
    const float* __restrict__ srcf, const u16* __restrict__ src16,
    u16* __restrict__ e16, float* __restrict__ dstf,
    const int* __restrict__ mem, const uint4* __restrict__ wcp,
    const float* __restrict__ bc)
{
  __shared__ u16   sW[6*8*64*8];   // 48 KB packed B-frags
  __shared__ u16   sA[64*192];     // 24 KB, row stride 384 B, XOR-swizzled
  __shared__ float sBc[DD];

  const int tid = threadIdx.x;
  {
    uint4* sw = (uint4*)sW;
    for (int i = tid; i < 3072; i += 256) sw[i] = wcp[i];
    if (tid < DD) sBc[tid] = bc[tid];
  }
  const int lane = tid & 63, wid = tid >> 6;
  const int colj = lane & 15, qw = lane >> 4;

  for (int rb = blockIdx.x; rb < NROWS/64; rb += gridDim.x){
    const int rowbase = rb * 64;
    __syncthreads();   // W staged (1st) / prior pass frag reads done
    // stage e-part (64x128 -> bf16 LDS)
    #pragma unroll
    for (int v = 0; v < 4; ++v){
      int f = (v*256 + tid) * 8;               // flat elem idx in 64x128
      int row = f >> 7, col = f & 127;
      uint4 out;
      if constexpr (S16){
        out = *(const uint4*)(src16 + (size_t)(rowbase+row)*DD + col);
      } else {
        const float4* s4 = (const float4*)(srcf + (size_t)(rowbase+row)*DD + col);
        float4 a = s4[0], b = s4[1];
        out = make_uint4(pk(a.x,a.y), pk(a.z,a.w), pk(b.x,b.y), pk(b.z,b.w));
      }
      *(uint4*)((char*)sA + row*384 + SWZ(row, col*2)) = out;
    }
    // stage mem-part (64x64 int 0/1 -> bf16)
    #pragma unroll
    for (int v = 0; v < 2; ++v){
      int f = (v*256 + tid) * 8;               // flat int idx in 64x64
      int row = f >> 6, col = f & 63;
      const int4* s4 = (const int4*)(mem + (size_t)(rowbase+row)*KK + col);
      int4 a = s4[0], b = s4[1];
      u32 p0 = (a.x?0x3F80u:0u) | ((a.y?0x3F80u:0u)<<16);
      u32 p1 = (a.z?0x3F80u:0u) | ((a.w?0x3F80u:0u)<<16);
      u32 p2 = (b.x?0x3F80u:0u) | ((b.y?0x3F80u:0u)<<16);
      u32 p3 = (b.z?0x3F80u:0u) | ((b.w?0x3F80u:0u)<<16);
      *(uint4*)((char*)sA + row*384 + SWZ(row, 256 + col*2)) =
        make_uint4(p0, p1, p2, p3);
    }
    __syncthreads();

    bf16x8 afr[6];
    #pragma unroll
    for (int kt = 0; kt < 6; ++kt){
      int row = wid*16 + colj;
      afr[kt] = *(bf16x8*)((char*)sA + row*384 + SWZ(row, kt*64 + qw*16));
    }
    f32x4 acc[8];
    #pragma unroll
    for (int nt = 0; nt < 8; ++nt) acc[nt] = (f32x4){0.f,0.f,0.f,0.f};
    #pragma unroll
    for (int nt = 0; nt < 8; ++nt){
      #pragma unroll
      for (int kt = 0; kt < 6; ++kt){
        bf16x8 bfr = *(bf16x8*)&sW[((kt*8 + nt)*64 + lane)*8];
        acc[nt] = __builtin_amdgcn_mfma_f32_16x16x32_bf16(afr[kt], bfr, acc[nt], 0,0,0);
      }
    }
    // epilogue: tanh + row l2norm (row i: 16-lane group qw, reg r)
    #pragma unroll
    for (int r = 0; r < 4; ++r){
      int grow = rowbase + wid*16 + qw*4 + r;
      float t[8], ss = 0.f;
      #pragma unroll
      for (int nt = 0; nt < 8; ++nt){
        t[nt] = tanhf(acc[nt][r] + sBc[nt*16 + colj]);
        ss += t[nt]*t[nt];
      }
      ss = qreduce16(ss);
      float sc = 1.0f / fmaxf(sqrtf(ss), 1e-12f);
      #pragma unroll
      for (int nt = 0; nt < 8; ++nt){
        float v = t[nt]*sc;
        if constexpr (W16)
          e16[(size_t)grow*DD + nt*16 + colj] = (u16)bfbits(v);
        if constexpr (WF32)
          dstf[(size_t)grow*DD + nt*16 + colj] = v;
      }
    }
  }
}

// --- relation update: 64 same-layer triples/block; B-frags straight from L2 --
template<bool S16, bool W16, bool WF32>
__global__ __launch_bounds__(256) void k_rel(
    const float* __restrict__ ef32, u16* __restrict__ e16,
    float* __restrict__ dstf,
    const int* __restrict__ subj, const int* __restrict__ obj,
    const uint4* __restrict__ wrp, const float* __restrict__ br,
    const int* __restrict__ offs, const int* __restrict__ bins)
{
  __shared__ u16   sA[64*256];   // 32 KB pairs bf16, row stride 512 B, swizzled
  __shared__ float sBr[256];
  __shared__ int   sS[BT], sO[BT];

  const int tid  = threadIdx.x;
  const int base = blockIdx.x * BT;
  if (base >= offs[LL]) return;
  int l = 0;
  while (l < LL-1 && base >= offs[l+1]) ++l;

  sBr[tid] = br[l*256 + tid];

  // gather pairs: 4 threads per triple, 128 B each
  const int ti = tid >> 2, q = tid & 3;
  int id = bins[base + ti];
  int rs = -1, ro = -1;
  if (id >= 0){ rs = subj[id]; ro = obj[id]; }
  if (q == 0){ sS[ti] = rs; sO[ti] = ro; }
  const int rr = (q < 2) ? rs : ro;
  if constexpr (S16){
    const u16* srcp = e16 + (size_t)rr*DD + (q & 1)*64;
    #pragma unroll
    for (int j = 0; j < 8; ++j){
      uint4 w = (id >= 0) ? ((const uint4*)srcp)[j] : make_uint4(0u,0u,0u,0u);
      *(uint4*)((char*)sA + ti*512 + SWZ(ti, q*128 + j*16)) = w;
    }
  } else {
    const float* srcp = ef32 + (size_t)rr*DD + (q & 1)*64;
    #pragma unroll
    for (int j = 0; j < 8; ++j){
      uint4 w;
      if (id >= 0){
        float4 a = ((const float4*)srcp)[2*j], b = ((const float4*)srcp)[2*j+1];
        w = make_uint4(pk(a.x,a.y), pk(a.z,a.w), pk(b.x,b.y), pk(b.z,b.w));
      } else w = make_uint4(0u,0u,0u,0u);
      *(uint4*)((char*)sA + ti*512 + SWZ(ti, q*128 + j*16)) = w;
    }
  }
  __syncthreads();

  const int lane = tid & 63, wid = tid >> 6;
  const int colj = lane & 15, qw = lane >> 4;

  bf16x8 afr[8];
  #pragma unroll
  for (int kt = 0; kt < 8; ++kt){
    int row = wid*16 + colj;
    afr[kt] = *(bf16x8*)((char*)sA + row*512 + SWZ(row, kt*64 + qw*16));
  }
  const uint4* wb = wrp + (size_t)l*8192 + lane;
  f32x4 acc[16];
  #pragma unroll
  for (int nt = 0; nt < 16; ++nt) acc[nt] = (f32x4){0.f,0.f,0.f,0.f};
  #pragma unroll
  for (int nt = 0; nt < 16; ++nt){
    #pragma unroll
    for (int kt = 0; kt < 8; ++kt){
      bf16x8 bfr = *(const bf16x8*)&wb[(kt*16 + nt)*64];
      acc[nt] = __builtin_amdgcn_mfma_f32_16x16x32_bf16(afr[kt], bfr, acc[nt], 0,0,0);
    }
  }
  // epilogue: per row, subj half (nt 0..7) and obj half (nt 8..15)
  #pragma unroll
  for (int r = 0; r < 4; ++r){
    int tri = wid*16 + qw*4 + r;
    float t[8], ss = 0.f;
    #pragma unroll
    for (int nt = 0; nt < 8; ++nt){
      t[nt] = tanhf(acc[nt][r] + sBr[nt*16 + colj]);
      ss += t[nt]*t[nt];
    }
    ss = qreduce16(ss);
    int srow = sS[tri];
    if (srow >= 0){
      float sc = 1.0f / fmaxf(sqrtf(ss), 1e-12f);
      #pragma unroll
      for (int nt = 0; nt < 8; ++nt){
        float v = t[nt]*sc;
        if constexpr (W16)
          e16[(size_t)srow*DD + nt*16 + colj] = (u16)bfbits(v);
        if constexpr (WF32)
          dstf[(size_t)srow*DD + nt*16 + colj] = v;
      }
    }
    float u[8], ss2 = 0.f;
    #pragma unroll
    for (int nt = 0; nt < 8; ++nt){
      u[nt] = tanhf(acc[nt+8][r] + sBr[(nt+8)*16 + colj]);
      ss2 += u[nt]*u[nt];
    }
    ss2 = qreduce16(ss2);
    int orow = sO[tri];
    if (orow >= 0){
      float sc = 1.0f / fmaxf(sqrtf(ss2), 1e-12f);
      #pragma unroll
      for (int nt = 0; nt < 8; ++nt){
        float v = u[nt]*sc;
        if constexpr (W16)
          e16[(size_t)orow*DD + nt*16 + colj] = (u16)bfbits(v);
        if constexpr (WF32)
          dstf[(size_t)orow*DD + nt*16 + colj] = v;
      }
    }
  }
}

extern "C" void kernel_launch(void* const* d_in, const int* in_sizes, int n_in,
                              void* d_out, int out_size, void* d_ws, size_t ws_size,
                              hipStream_t stream) {
  (void)in_sizes; (void)n_in; (void)out_size;
  const float* emb  = (const float*)d_in[0];
  const int*   mem  = (const int*)  d_in[1];
  const int*   subj = (const int*)  d_in[2];
  const int*   obj  = (const int*)  d_in[3];
  const int*   lay  = (const int*)  d_in[4];
  const float* Wc   = (const float*)d_in[5];
  const float* bc   = (const float*)d_in[6];
  const float* Wr   = (const float*)d_in[7];
  const float* br   = (const float*)d_in[8];

  float* e   = (float*)d_out;
  char*  wsb = (char*)d_ws;
  int*   offs = (int*)(wsb + WS_OFFS);
  int*   bins = (int*)(wsb + WS_BINS);
  uint4* wcp  = (uint4*)(wsb + WS_WCP);
  uint4* wrp  = (uint4*)(wsb + WS_WRP);
  u16*   e16  = (u16*)(wsb + WS_E16);

  hipMemsetAsync(wsb + WS_BINS, 0xFF, PADT*4, stream);
  k_prep<<<268, 256, 0, stream>>>(Wc, Wr, wcp, wrp);
  k_bin <<<1, BINTH, 0, stream>>>(lay, offs, bins);

  if (ws_size >= WS_NEED){
    // bf16-resident e path
    k_class<false,true,false><<<512, 256, 0, stream>>>(emb, nullptr, e16, nullptr, mem, wcp, bc);
    k_rel  <true,true,false><<<PADT/BT, 256, 0, stream>>>(nullptr, e16, nullptr, subj, obj, wrp, br, offs, bins);
    k_class<true,true,true><<<512, 256, 0, stream>>>(nullptr, e16, e16, e, mem, wcp, bc);
    k_rel  <true,false,true><<<PADT/BT, 256, 0, stream>>>(nullptr, e16, e, subj, obj, wrp, br, offs, bins);
  } else {
    // f32 fallback (e lives in d_out)
    hipMemcpyAsync(e, emb, (size_t)NROWS*DD*sizeof(float),
                   hipMemcpyDeviceToDevice, stream);
    for (int it = 0; it < 2; ++it){
      k_class<false,false,true><<<512, 256, 0, stream>>>(e, nullptr, nullptr, e, mem, wcp, bc);
      k_rel  <false,false,true><<<PADT/BT, 256, 0, stream>>>(e, nullptr, e, subj, obj, wrp, br, offs, bins);
    }
  }
}

// Round 4
// 293.791 us; speedup vs baseline: 5.7360x; 1.3641x over previous
//
#include <hip/hip_runtime.h>
#include <hip/hip_bf16.h>

// ---------------------------------------------------------------------------
// RRN, MFMA version, parallel scan-binned, bf16-resident e.
//   iter: e = l2norm(tanh([e;mem] @ Wc + bc))            (K=192 GEMM, MFMA)
//         per triple (unique rows): out = tanh([e_s;e_o] @ Wr[l] + br[l])
//         e[s]=l2norm(out[:128]); e[o]=l2norm(out[128:])  (layer-binned MFMA)
// subj ∪ obj are distinct rows -> in-place update race-free.
// e kept in bf16 (ws) between ops (consumers round to bf16 anyway -> identical
// math, half the traffic). memberships bit-packed on the fly in iter-0.
// Final iter writes f32 to d_out (class full-write, rel row-overwrite).
// ---------------------------------------------------------------------------

#define NROWS 200000
#define DD    128
#define KK    64
#define TT    50000
#define LL    8
#define BT    64
#define PADT  50560            // 64*790 >= 50000 + 8*63

#define NB    100              // binning blocks
#define CHB   500              // elements per binning block (NB*CHB == TT)
#define PL    8                // elements per lane (64*8 >= CHB)
#define PREPB 268              // weight-packing blocks in k_prep (268*256 == 68608)

// ws layout (bytes)
#define WS_OFFS   0
#define WS_CNT    64                        // NB*LL ints = 3200
#define WS_BASE   4096                      // NB*LL ints
#define WS_BINS   8192                      // PADT*4 = 202240
#define WS_WCP    210432                    // 48 KB, 16B aligned
#define WS_WRP    (WS_WCP + 6*8*64*16)      // 259584; 1 MB
#define WS_MB     (WS_WRP + 8*8*16*64*16)   // 1308160; 1.6 MB bit-packed mem
#define WS_E16    (WS_MB + NROWS*8)         // 2908160; 51.2 MB
#define WS_NEED   (WS_E16 + (size_t)NROWS*DD*2)

typedef unsigned short u16;
typedef unsigned int   u32;
typedef unsigned long long u64;
typedef unsigned char  u8;
typedef __attribute__((ext_vector_type(8))) short bf16x8;
typedef __attribute__((ext_vector_type(4))) float f32x4;

#define SWZ(row, byte) ((byte) ^ (((row)&7)<<4))

__device__ __forceinline__ u32 bfbits(float f){
  __hip_bfloat16 h = __float2bfloat16(f);
  return (u32)*reinterpret_cast<unsigned short*>(&h);
}
__device__ __forceinline__ u32 pk(float lo, float hi){
  return bfbits(lo) | (bfbits(hi) << 16);
}
__device__ __forceinline__ float qreduce16(float ss){
  ss += __shfl_xor(ss, 1, 64);
  ss += __shfl_xor(ss, 2, 64);
  ss += __shfl_xor(ss, 4, 64);
  ss += __shfl_xor(ss, 8, 64);
  return ss;
}

// --- prep: pack Wc/Wr into MFMA B-frag order; extra blocks: bin counts ------
__global__ __launch_bounds__(256) void k_prep(
    const float* __restrict__ Wc, const float* __restrict__ Wr,
    uint4* __restrict__ wcp, uint4* __restrict__ wrp,
    const int* __restrict__ layer, int* __restrict__ cnt)
{
  if (blockIdx.x >= PREPB){
    const int bb = blockIdx.x - PREPB, lane = threadIdx.x;
    if (lane >= 64) return;
    const int lim = bb*CHB + CHB;
    int i0 = bb*CHB + lane*PL, i1 = i0 + PL; if (i1 > lim) i1 = lim;
    int c[LL] = {0,0,0,0,0,0,0,0};
    for (int i = i0; i < i1; ++i){
      int l = layer[i];
      #pragma unroll
      for (int k = 0; k < LL; ++k) c[k] += (l == k);
    }
    #pragma unroll
    for (int k = 0; k < LL; ++k){
      int v = c[k];
      v += __shfl_xor(v, 1, 64); v += __shfl_xor(v, 2, 64);
      v += __shfl_xor(v, 4, 64); v += __shfl_xor(v, 8, 64);
      v += __shfl_xor(v, 16, 64); v += __shfl_xor(v, 32, 64);
      if (lane == k) cnt[bb*LL + k] = v;
    }
    return;
  }
  int id = blockIdx.x*blockDim.x + threadIdx.x;
  if (id < 3072){                       // wcp: kt 0..5, nt 0..7
    int lane = id & 63, nt = (id >> 6) & 7, kt = id >> 9;
    int k0 = kt*32 + (lane>>4)*8, n = nt*16 + (lane&15);
    u32 p[4];
    #pragma unroll
    for (int e2 = 0; e2 < 4; ++e2)
      p[e2] = pk(Wc[(k0 + 2*e2)*DD + n], Wc[(k0 + 2*e2 + 1)*DD + n]);
    wcp[id] = make_uint4(p[0], p[1], p[2], p[3]);
  } else if (id < 3072 + 65536){        // wrp: l, kt 0..7, nt 0..15
    int id2 = id - 3072;
    int lane = id2 & 63, nt = (id2>>6) & 15, kt = (id2>>10) & 7, l = id2 >> 13;
    int k0 = kt*32 + (lane>>4)*8, n = nt*16 + (lane&15);
    const float* w = Wr + (size_t)l*65536;
    u32 p[4];
    #pragma unroll
    for (int e2 = 0; e2 < 4; ++e2)
      p[e2] = pk(w[(k0 + 2*e2)*256 + n], w[(k0 + 2*e2 + 1)*256 + n]);
    wrp[id2] = make_uint4(p[0], p[1], p[2], p[3]);
  }
}

// --- bin2: offsets + per-block bases + pad fill (1 tiny block) ---------------
__global__ __launch_bounds__(64) void k_bin2(const int* __restrict__ cnt,
                                             int* __restrict__ offs,
                                             int* __restrict__ gbase,
                                             int* __restrict__ bins)
{
  __shared__ int pre[NB][LL];
  __shared__ int tot[LL], soffs[LL+1];
  const int t = threadIdx.x;
  if (t < LL){
    int acc = 0;
    for (int bb = 0; bb < NB; ++bb){ pre[bb][t] = acc; acc += cnt[bb*LL + t]; }
    tot[t] = acc;
  }
  __syncthreads();
  if (t == 0){
    int acc = 0;
    for (int l = 0; l < LL; ++l){
      soffs[l] = acc; offs[l] = acc;
      acc += ((tot[l] + BT - 1)/BT)*BT;
    }
    soffs[LL] = acc; offs[LL] = acc;
  }
  __syncthreads();
  for (int idx = t; idx < NB*LL; idx += 64){
    int bb = idx >> 3, k = idx & 7;
    gbase[idx] = soffs[k] + pre[bb][k];
  }
  const int k = t >> 3, sub = t & 7;
  const int sz = soffs[k+1] - soffs[k];
  for (int i = tot[k] + sub; i < sz; i += 8) bins[soffs[k] + i] = -1;
}

// --- bin3: ordered scatter (NB one-wave blocks) -------------------------------
__global__ __launch_bounds__(64) void k_bin3(const int* __restrict__ layer,
                                             const int* __restrict__ gbase,
                                             int* __restrict__ bins)
{
  const int bb = blockIdx.x, lane = threadIdx.x;
  const int lim = bb*CHB + CHB;
  int i0 = bb*CHB + lane*PL, i1 = i0 + PL; if (i1 > lim) i1 = lim;
  int c[LL] = {0,0,0,0,0,0,0,0};
  for (int i = i0; i < i1; ++i){
    int l = layer[i];
    #pragma unroll
    for (int k = 0; k < LL; ++k) c[k] += (l == k);
  }
  int start[LL];
  #pragma unroll
  for (int k = 0; k < LL; ++k){
    int v = c[k];
    #pragma unroll
    for (int d = 1; d < 64; d <<= 1){
      int u = __shfl_up(v, d, 64);
      if (lane >= d) v += u;
    }
    start[k] = gbase[bb*LL + k] + v - c[k];
  }
  for (int i = i0; i < i1; ++i){
    int l = layer[i];
    #pragma unroll
    for (int k = 0; k < LL; ++k)
      if (l == k) bins[start[k]++] = i;
  }
}

// --- class update: dst = l2norm(tanh([src;mem] @ Wc + bc)) -------------------
// S16: read e from e16 (else f32).  MBITS: read bit-packed mem (else raw ints,
// and write the bit-pack for the next iteration).  W16/WF32: output targets.
template<bool S16, bool MBITS, bool W16, bool WF32>
__global__ __launch_bounds__(256) void k_class(
    const float* __restrict__ srcf, const u16* __restrict__ src16,
    u16* __restrict__ e16, float* __restrict__ dstf,
    const int* __restrict__ mem, u64* __restrict__ mbits,
    const uint4* __restrict__ wcp, const float* __restrict__ bc)
{
  __shared__ u16   sW[6*8*64*8];   // 48 KB packed B-frags
  __shared__ u16   sA[64*192];     // 24 KB, row stride 384 B, XOR-swizzled
  __shared__ float sBc[DD];

  const int tid = threadIdx.x;
  {
    uint4* sw = (uint4*)sW;
    for (int i = tid; i < 3072; i += 256) sw[i] = wcp[i];
    if (tid < DD) sBc[tid] = bc[tid];
  }
  const int lane = tid & 63, wid = tid >> 6;
  const int colj = lane & 15, qw = lane >> 4;

  for (int rb = blockIdx.x; rb < NROWS/64; rb += gridDim.x){
    const int rowbase = rb * 64;
    __syncthreads();   // W staged (1st) / prior pass frag reads done
    // stage e-part (64x128 -> bf16 LDS)
    #pragma unroll
    for (int v = 0; v < 4; ++v){
      int f = (v*256 + tid) * 8;               // flat elem idx in 64x128
      int row = f >> 7, col = f & 127;
      uint4 out;
      if constexpr (S16){
        out = *(const uint4*)(src16 + (size_t)(rowbase+row)*DD + col);
      } else {
        const float4* s4 = (const float4*)(srcf + (size_t)(rowbase+row)*DD + col);
        float4 a = s4[0], b = s4[1];
        out = make_uint4(pk(a.x,a.y), pk(a.z,a.w), pk(b.x,b.y), pk(b.z,b.w));
      }
      *(uint4*)((char*)sA + row*384 + SWZ(row, col*2)) = out;
    }
    // stage mem-part (64x64 -> bf16 LDS)
    if constexpr (MBITS){
      const int r = tid >> 2, q = tid & 3;
      u64 m = mbits[rowbase + r];
      u32 s = (u32)(m >> (q*16)) & 0xFFFFu;
      u32 p[8];
      #pragma unroll
      for (int jj = 0; jj < 8; ++jj){
        u32 lo = (s >> (2*jj))     & 1u;
        u32 hi = (s >> (2*jj + 1)) & 1u;
        p[jj] = (lo ? 0x3F80u : 0u) | (hi ? 0x3F800000u : 0u);
      }
      *(uint4*)((char*)sA + r*384 + SWZ(r, 256 + q*32))      = make_uint4(p[0],p[1],p[2],p[3]);
      *(uint4*)((char*)sA + r*384 + SWZ(r, 256 + q*32 + 16)) = make_uint4(p[4],p[5],p[6],p[7]);
    } else {
      u8* mb8 = (u8*)mbits;
      #pragma unroll
      for (int v = 0; v < 2; ++v){
        int f = (v*256 + tid) * 8;             // flat int idx in 64x64
        int row = f >> 6, col = f & 63;
        const int4* s4 = (const int4*)(mem + (size_t)(rowbase+row)*KK + col);
        int4 a = s4[0], b = s4[1];
        u32 p0 = (a.x?0x3F80u:0u) | ((a.y?0x3F80u:0u)<<16);
        u32 p1 = (a.z?0x3F80u:0u) | ((a.w?0x3F80u:0u)<<16);
        u32 p2 = (b.x?0x3F80u:0u) | ((b.y?0x3F80u:0u)<<16);
        u32 p3 = (b.z?0x3F80u:0u) | ((b.w?0x3F80u:0u)<<16);
        *(uint4*)((char*)sA + row*384 + SWZ(row, 256 + col*2)) =
          make_uint4(p0, p1, p2, p3);
        u8 byte = (u8)((a.x!=0) | ((a.y!=0)<<1) | ((a.z!=0)<<2) | ((a.w!=0)<<3)
                 | ((b.x!=0)<<4) | ((b.y!=0)<<5) | ((b.z!=0)<<6) | ((b.w!=0)<<7));
        mb8[(size_t)(rowbase+row)*8 + (col>>3)] = byte;
      }
    }
    __syncthreads();

    bf16x8 afr[6];
    #pragma unroll
    for (int kt = 0; kt < 6; ++kt){
      int row = wid*16 + colj;
      afr[kt] = *(bf16x8*)((char*)sA + row*384 + SWZ(row, kt*64 + qw*16));
    }
    f32x4 acc[8];
    #pragma unroll
    for (int nt = 0; nt < 8; ++nt) acc[nt] = (f32x4){0.f,0.f,0.f,0.f};
    #pragma unroll
    for (int nt = 0; nt < 8; ++nt){
      #pragma unroll
      for (int kt = 0; kt < 6; ++kt){
        bf16x8 bfr = *(bf16x8*)&sW[((kt*8 + nt)*64 + lane)*8];
        acc[nt] = __builtin_amdgcn_mfma_f32_16x16x32_bf16(afr[kt], bfr, acc[nt], 0,0,0);
      }
    }
    // epilogue: tanh + row l2norm (row: 16-lane group qw, reg r)
    #pragma unroll
    for (int r = 0; r < 4; ++r){
      int grow = rowbase + wid*16 + qw*4 + r;
      float t[8], ss = 0.f;
      #pragma unroll
      for (int nt = 0; nt < 8; ++nt){
        t[nt] = tanhf(acc[nt][r] + sBc[nt*16 + colj]);
        ss += t[nt]*t[nt];
      }
      ss = qreduce16(ss);
      float sc = 1.0f / fmaxf(sqrtf(ss), 1e-12f);
      #pragma unroll
      for (int nt = 0; nt < 8; ++nt){
        float v = t[nt]*sc;
        if constexpr (W16)
          e16[(size_t)grow*DD + nt*16 + colj] = (u16)bfbits(v);
        if constexpr (WF32)
          dstf[(size_t)grow*DD + nt*16 + colj] = v;
      }
    }
  }
}

// --- relation update: 64 same-layer triples/block; B-frags straight from L2 --
template<bool S16, bool W16, bool WF32>
__global__ __launch_bounds__(256) void k_rel(
    const float* __restrict__ ef32, u16* __restrict__ e16,
    float* __restrict__ dstf,
    const int* __restrict__ subj, const int* __restrict__ obj,
    const uint4* __restrict__ wrp, const float* __restrict__ br,
    const int* __restrict__ offs, const int* __restrict__ bins)
{
  __shared__ u16   sA[64*256];   // 32 KB pairs bf16, row stride 512 B, swizzled
  __shared__ float sBr[256];
  __shared__ int   sS[BT], sO[BT];

  const int tid  = threadIdx.x;
  const int base = blockIdx.x * BT;
  if (base >= offs[LL]) return;
  int l = 0;
  while (l < LL-1 && base >= offs[l+1]) ++l;

  sBr[tid] = br[l*256 + tid];

  // gather pairs: 4 threads per triple, 128 B each
  const int ti = tid >> 2, q = tid & 3;
  int id = bins[base + ti];
  int rs = -1, ro = -1;
  if (id >= 0){ rs = subj[id]; ro = obj[id]; }
  if (q == 0){ sS[ti] = rs; sO[ti] = ro; }
  const int rr = (q < 2) ? rs : ro;
  if constexpr (S16){
    const u16* srcp = e16 + (size_t)rr*DD + (q & 1)*64;
    #pragma unroll
    for (int j = 0; j < 8; ++j){
      uint4 w = (id >= 0) ? ((const uint4*)srcp)[j] : make_uint4(0u,0u,0u,0u);
      *(uint4*)((char*)sA + ti*512 + SWZ(ti, q*128 + j*16)) = w;
    }
  } else {
    const float* srcp = ef32 + (size_t)rr*DD + (q & 1)*64;
    #pragma unroll
    for (int j = 0; j < 8; ++j){
      uint4 w;
      if (id >= 0){
        float4 a = ((const float4*)srcp)[2*j], b = ((const float4*)srcp)[2*j+1];
        w = make_uint4(pk(a.x,a.y), pk(a.z,a.w), pk(b.x,b.y), pk(b.z,b.w));
      } else w = make_uint4(0u,0u,0u,0u);
      *(uint4*)((char*)sA + ti*512 + SWZ(ti, q*128 + j*16)) = w;
    }
  }
  __syncthreads();

  const int lane = tid & 63, wid = tid >> 6;
  const int colj = lane & 15, qw = lane >> 4;

  bf16x8 afr[8];
  #pragma unroll
  for (int kt = 0; kt < 8; ++kt){
    int row = wid*16 + colj;
    afr[kt] = *(bf16x8*)((char*)sA + row*512 + SWZ(row, kt*64 + qw*16));
  }
  const uint4* wb = wrp + (size_t)l*8192 + lane;
  f32x4 acc[16];
  #pragma unroll
  for (int nt = 0; nt < 16; ++nt) acc[nt] = (f32x4){0.f,0.f,0.f,0.f};
  #pragma unroll
  for (int nt = 0; nt < 16; ++nt){
    #pragma unroll
    for (int kt = 0; kt < 8; ++kt){
      bf16x8 bfr = *(const bf16x8*)&wb[(kt*16 + nt)*64];
      acc[nt] = __builtin_amdgcn_mfma_f32_16x16x32_bf16(afr[kt], bfr, acc[nt], 0,0,0);
    }
  }
  // epilogue: per row, subj half (nt 0..7) and obj half (nt 8..15)
  #pragma unroll
  for (int r = 0; r < 4; ++r){
    int tri = wid*16 + qw*4 + r;
    float t[8], ss = 0.f;
    #pragma unroll
    for (int nt = 0; nt < 8; ++nt){
      t[nt] = tanhf(acc[nt][r] + sBr[nt*16 + colj]);
      ss += t[nt]*t[nt];
    }
    ss = qreduce16(ss);
    int srow = sS[tri];
    if (srow >= 0){
      float sc = 1.0f / fmaxf(sqrtf(ss), 1e-12f);
      #pragma unroll
      for (int nt = 0; nt < 8; ++nt){
        float v = t[nt]*sc;
        if constexpr (W16)
          e16[(size_t)srow*DD + nt*16 + colj] = (u16)bfbits(v);
        if constexpr (WF32)
          dstf[(size_t)srow*DD + nt*16 + colj] = v;
      }
    }
    float u[8], ss2 = 0.f;
    #pragma unroll
    for (int nt = 0; nt < 8; ++nt){
      u[nt] = tanhf(acc[nt+8][r] + sBr[(nt+8)*16 + colj]);
      ss2 += u[nt]*u[nt];
    }
    ss2 = qreduce16(ss2);
    int orow = sO[tri];
    if (orow >= 0){
      float sc = 1.0f / fmaxf(sqrtf(ss2), 1e-12f);
      #pragma unroll
      for (int nt = 0; nt < 8; ++nt){
        float v = u[nt]*sc;
        if constexpr (W16)
          e16[(size_t)orow*DD + nt*16 + colj] = (u16)bfbits(v);
        if constexpr (WF32)
          dstf[(size_t)orow*DD + nt*16 + colj] = v;
      }
    }
  }
}

extern "C" void kernel_launch(void* const* d_in, const int* in_sizes, int n_in,
                              void* d_out, int out_size, void* d_ws, size_t ws_size,
                              hipStream_t stream) {
  (void)in_sizes; (void)n_in; (void)out_size;
  const float* emb  = (const float*)d_in[0];
  const int*   mem  = (const int*)  d_in[1];
  const int*   subj = (const int*)  d_in[2];
  const int*   obj  = (const int*)  d_in[3];
  const int*   lay  = (const int*)  d_in[4];
  const float* Wc   = (const float*)d_in[5];
  const float* bc   = (const float*)d_in[6];
  const float* Wr   = (const float*)d_in[7];
  const float* br   = (const float*)d_in[8];

  float* e   = (float*)d_out;
  char*  wsb = (char*)d_ws;
  int*   offs  = (int*)(wsb + WS_OFFS);
  int*   cnt   = (int*)(wsb + WS_CNT);
  int*   gbase = (int*)(wsb + WS_BASE);
  int*   bins  = (int*)(wsb + WS_BINS);
  uint4* wcp   = (uint4*)(wsb + WS_WCP);
  uint4* wrp   = (uint4*)(wsb + WS_WRP);
  u64*   mbits = (u64*)(wsb + WS_MB);
  u16*   e16   = (u16*)(wsb + WS_E16);

  k_prep<<<PREPB + NB, 256, 0, stream>>>(Wc, Wr, wcp, wrp, lay, cnt);
  k_bin2<<<1, 64, 0, stream>>>(cnt, offs, gbase, bins);
  k_bin3<<<NB, 64, 0, stream>>>(lay, gbase, bins);

  if (ws_size >= WS_NEED){
    // bf16-resident e path
    k_class<false,false,true,false><<<512, 256, 0, stream>>>(
        emb, nullptr, e16, nullptr, mem, mbits, wcp, bc);
    k_rel<true,true,false><<<PADT/BT, 256, 0, stream>>>(
        nullptr, e16, nullptr, subj, obj, wrp, br, offs, bins);
    k_class<true,true,false,true><<<512, 256, 0, stream>>>(
        nullptr, e16, nullptr, e, mem, mbits, wcp, bc);
    k_rel<false,false,true><<<PADT/BT, 256, 0, stream>>>(
        e, nullptr, e, subj, obj, wrp, br, offs, bins);
  } else {
    // f32 fallback (e lives in d_out)
    k_class<false,false,false,true><<<512, 256, 0, stream>>>(
        emb, nullptr, nullptr, e, mem, mbits, wcp, bc);
    k_rel<false,false,true><<<PADT/BT, 256, 0, stream>>>(
        e, nullptr, e, subj, obj, wrp, br, offs, bins);
    k_class<false,true,false,true><<<512, 256, 0, stream>>>(
        e, nullptr, nullptr, e, mem, mbits, wcp, bc);
    k_rel<false,false,true><<<PADT/BT, 256, 0, stream>>>(
        e, nullptr, e, subj, obj, wrp, br, offs, bins);
  }
}

// Round 5
// 204.820 us; speedup vs baseline: 8.2276x; 1.4344x over previous
//
#include <hip/hip_runtime.h>
#include <hip/hip_bf16.h>

// ---------------------------------------------------------------------------
// RRN, MFMA version, parallel scan-binned, bf16-resident e.
//   iter: e = l2norm(tanh([e;mem] @ Wc + bc))            (K=192 GEMM, MFMA)
//         per triple (unique rows): out = tanh([e_s;e_o] @ Wr[l] + br[l])
//         e[s]=l2norm(out[:128]); e[o]=l2norm(out[128:])  (layer-binned MFMA)
// subj ∪ obj are distinct rows -> in-place update race-free.
// k_rel wave decomposition: wave w = all 64 triples x nt[4w..4w+4) so each
// weight frag (L2) feeds 4 MFMAs; depth-2 prefetch hides L2 latency.
// ---------------------------------------------------------------------------

#define NROWS 200000
#define DD    128
#define KK    64
#define TT    50000
#define LL    8
#define BT    64
#define PADT  50560            // 64*790 >= 50000 + 8*63

#define NB    100              // binning blocks
#define CHB   500              // elements per binning block (NB*CHB == TT)
#define PL    8                // elements per lane (64*8 >= CHB)
#define PREPB 268              // weight-packing blocks in k_prep

// ws layout (bytes)
#define WS_OFFS   0
#define WS_CNT    64                        // NB*LL ints = 3200
#define WS_BASE   4096                      // NB*LL ints
#define WS_BINS   8192                      // PADT*4 = 202240
#define WS_WCP    210432                    // 48 KB, 16B aligned
#define WS_WRP    (WS_WCP + 6*8*64*16)      // 259584; 1 MB
#define WS_MB     (WS_WRP + 8*8*16*64*16)   // 1308160; 1.6 MB bit-packed mem
#define WS_E16    (WS_MB + NROWS*8)         // 2908160; 51.2 MB
#define WS_NEED   (WS_E16 + (size_t)NROWS*DD*2)

typedef unsigned short u16;
typedef unsigned int   u32;
typedef unsigned long long u64;
typedef unsigned char  u8;
typedef __attribute__((ext_vector_type(8))) short bf16x8;
typedef __attribute__((ext_vector_type(4))) float f32x4;

#define SWZ(row, byte) ((byte) ^ (((row)&7)<<4))

__device__ __forceinline__ u32 bfbits(float f){
  __hip_bfloat16 h = __float2bfloat16(f);
  return (u32)*reinterpret_cast<unsigned short*>(&h);
}
__device__ __forceinline__ u32 pk(float lo, float hi){
  return bfbits(lo) | (bfbits(hi) << 16);
}
__device__ __forceinline__ float qreduce16(float ss){
  ss += __shfl_xor(ss, 1, 64);
  ss += __shfl_xor(ss, 2, 64);
  ss += __shfl_xor(ss, 4, 64);
  ss += __shfl_xor(ss, 8, 64);
  return ss;
}

// --- prep: pack Wc/Wr into MFMA B-frag order; extra blocks: bin counts ------
__global__ __launch_bounds__(256) void k_prep(
    const float* __restrict__ Wc, const float* __restrict__ Wr,
    uint4* __restrict__ wcp, uint4* __restrict__ wrp,
    const int* __restrict__ layer, int* __restrict__ cnt)
{
  if (blockIdx.x >= PREPB){
    const int bb = blockIdx.x - PREPB, lane = threadIdx.x;
    if (lane >= 64) return;
    const int lim = bb*CHB + CHB;
    int i0 = bb*CHB + lane*PL, i1 = i0 + PL; if (i1 > lim) i1 = lim;
    int c[LL] = {0,0,0,0,0,0,0,0};
    for (int i = i0; i < i1; ++i){
      int l = layer[i];
      #pragma unroll
      for (int k = 0; k < LL; ++k) c[k] += (l == k);
    }
    #pragma unroll
    for (int k = 0; k < LL; ++k){
      int v = c[k];
      v += __shfl_xor(v, 1, 64); v += __shfl_xor(v, 2, 64);
      v += __shfl_xor(v, 4, 64); v += __shfl_xor(v, 8, 64);
      v += __shfl_xor(v, 16, 64); v += __shfl_xor(v, 32, 64);
      if (lane == k) cnt[bb*LL + k] = v;
    }
    return;
  }
  int id = blockIdx.x*blockDim.x + threadIdx.x;
  if (id < 3072){                       // wcp: kt 0..5, nt 0..7
    int lane = id & 63, nt = (id >> 6) & 7, kt = id >> 9;
    int k0 = kt*32 + (lane>>4)*8, n = nt*16 + (lane&15);
    u32 p[4];
    #pragma unroll
    for (int e2 = 0; e2 < 4; ++e2)
      p[e2] = pk(Wc[(k0 + 2*e2)*DD + n], Wc[(k0 + 2*e2 + 1)*DD + n]);
    wcp[id] = make_uint4(p[0], p[1], p[2], p[3]);
  } else if (id < 3072 + 65536){        // wrp: l, kt 0..7, nt 0..15
    int id2 = id - 3072;
    int lane = id2 & 63, nt = (id2>>6) & 15, kt = (id2>>10) & 7, l = id2 >> 13;
    int k0 = kt*32 + (lane>>4)*8, n = nt*16 + (lane&15);
    const float* w = Wr + (size_t)l*65536;
    u32 p[4];
    #pragma unroll
    for (int e2 = 0; e2 < 4; ++e2)
      p[e2] = pk(w[(k0 + 2*e2)*256 + n], w[(k0 + 2*e2 + 1)*256 + n]);
    wrp[id2] = make_uint4(p[0], p[1], p[2], p[3]);
  }
}

// --- bin2: offsets + per-block bases + pad fill (1 tiny block) ---------------
__global__ __launch_bounds__(64) void k_bin2(const int* __restrict__ cnt,
                                             int* __restrict__ offs,
                                             int* __restrict__ gbase,
                                             int* __restrict__ bins)
{
  __shared__ int pre[NB][LL];
  __shared__ int tot[LL], soffs[LL+1];
  const int t = threadIdx.x;
  if (t < LL){
    int acc = 0;
    for (int bb = 0; bb < NB; ++bb){ pre[bb][t] = acc; acc += cnt[bb*LL + t]; }
    tot[t] = acc;
  }
  __syncthreads();
  if (t == 0){
    int acc = 0;
    for (int l = 0; l < LL; ++l){
      soffs[l] = acc; offs[l] = acc;
      acc += ((tot[l] + BT - 1)/BT)*BT;
    }
    soffs[LL] = acc; offs[LL] = acc;
  }
  __syncthreads();
  for (int idx = t; idx < NB*LL; idx += 64){
    int bb = idx >> 3, k = idx & 7;
    gbase[idx] = soffs[k] + pre[bb][k];
  }
  const int k = t >> 3, sub = t & 7;
  const int sz = soffs[k+1] - soffs[k];
  for (int i = tot[k] + sub; i < sz; i += 8) bins[soffs[k] + i] = -1;
}

// --- bin3: ordered scatter (NB one-wave blocks) -------------------------------
__global__ __launch_bounds__(64) void k_bin3(const int* __restrict__ layer,
                                             const int* __restrict__ gbase,
                                             int* __restrict__ bins)
{
  const int bb = blockIdx.x, lane = threadIdx.x;
  const int lim = bb*CHB + CHB;
  int i0 = bb*CHB + lane*PL, i1 = i0 + PL; if (i1 > lim) i1 = lim;
  int c[LL] = {0,0,0,0,0,0,0,0};
  for (int i = i0; i < i1; ++i){
    int l = layer[i];
    #pragma unroll
    for (int k = 0; k < LL; ++k) c[k] += (l == k);
  }
  int start[LL];
  #pragma unroll
  for (int k = 0; k < LL; ++k){
    int v = c[k];
    #pragma unroll
    for (int d = 1; d < 64; d <<= 1){
      int u = __shfl_up(v, d, 64);
      if (lane >= d) v += u;
    }
    start[k] = gbase[bb*LL + k] + v - c[k];
  }
  for (int i = i0; i < i1; ++i){
    int l = layer[i];
    #pragma unroll
    for (int k = 0; k < LL; ++k)
      if (l == k) bins[start[k]++] = i;
  }
}

// --- class update: dst = l2norm(tanh([src;mem] @ Wc + bc)) -------------------
template<bool S16, bool MBITS, bool W16, bool WF32>
__global__ __launch_bounds__(256) void k_class(
    const float* __restrict__ srcf, const u16* __restrict__ src16,
    u16* __restrict__ e16, float* __restrict__ dstf,
    const int* __restrict__ mem, u64* __restrict__ mbits,
    const uint4* __restrict__ wcp, const float* __restrict__ bc)
{
  __shared__ u16   sW[6*8*64*8];   // 48 KB packed B-frags
  __shared__ u16   sA[64*192];     // 24 KB, row stride 384 B, XOR-swizzled
  __shared__ float sBc[DD];

  const int tid = threadIdx.x;
  {
    uint4* sw = (uint4*)sW;
    for (int i = tid; i < 3072; i += 256) sw[i] = wcp[i];
    if (tid < DD) sBc[tid] = bc[tid];
  }
  const int lane = tid & 63, wid = tid >> 6;
  const int colj = lane & 15, qw = lane >> 4;

  for (int rb = blockIdx.x; rb < NROWS/64; rb += gridDim.x){
    const int rowbase = rb * 64;
    __syncthreads();   // W staged (1st) / prior pass frag reads done
    // stage e-part (64x128 -> bf16 LDS)
    #pragma unroll
    for (int v = 0; v < 4; ++v){
      int f = (v*256 + tid) * 8;               // flat elem idx in 64x128
      int row = f >> 7, col = f & 127;
      uint4 out;
      if constexpr (S16){
        out = *(const uint4*)(src16 + (size_t)(rowbase+row)*DD + col);
      } else {
        const float4* s4 = (const float4*)(srcf + (size_t)(rowbase+row)*DD + col);
        float4 a = s4[0], b = s4[1];
        out = make_uint4(pk(a.x,a.y), pk(a.z,a.w), pk(b.x,b.y), pk(b.z,b.w));
      }
      *(uint4*)((char*)sA + row*384 + SWZ(row, col*2)) = out;
    }
    // stage mem-part (64x64 -> bf16 LDS)
    if constexpr (MBITS){
      const int r = tid >> 2, q = tid & 3;
      u64 m = mbits[rowbase + r];
      u32 s = (u32)(m >> (q*16)) & 0xFFFFu;
      u32 p[8];
      #pragma unroll
      for (int jj = 0; jj < 8; ++jj){
        u32 lo = (s >> (2*jj))     & 1u;
        u32 hi = (s >> (2*jj + 1)) & 1u;
        p[jj] = (lo ? 0x3F80u : 0u) | (hi ? 0x3F800000u : 0u);
      }
      *(uint4*)((char*)sA + r*384 + SWZ(r, 256 + q*32))      = make_uint4(p[0],p[1],p[2],p[3]);
      *(uint4*)((char*)sA + r*384 + SWZ(r, 256 + q*32 + 16)) = make_uint4(p[4],p[5],p[6],p[7]);
    } else {
      u8* mb8 = (u8*)mbits;
      #pragma unroll
      for (int v = 0; v < 2; ++v){
        int f = (v*256 + tid) * 8;             // flat int idx in 64x64
        int row = f >> 6, col = f & 63;
        const int4* s4 = (const int4*)(mem + (size_t)(rowbase+row)*KK + col);
        int4 a = s4[0], b = s4[1];
        u32 p0 = (a.x?0x3F80u:0u) | ((a.y?0x3F80u:0u)<<16);
        u32 p1 = (a.z?0x3F80u:0u) | ((a.w?0x3F80u:0u)<<16);
        u32 p2 = (b.x?0x3F80u:0u) | ((b.y?0x3F80u:0u)<<16);
        u32 p3 = (b.z?0x3F80u:0u) | ((b.w?0x3F80u:0u)<<16);
        *(uint4*)((char*)sA + row*384 + SWZ(row, 256 + col*2)) =
          make_uint4(p0, p1, p2, p3);
        u8 byte = (u8)((a.x!=0) | ((a.y!=0)<<1) | ((a.z!=0)<<2) | ((a.w!=0)<<3)
                 | ((b.x!=0)<<4) | ((b.y!=0)<<5) | ((b.z!=0)<<6) | ((b.w!=0)<<7));
        mb8[(size_t)(rowbase+row)*8 + (col>>3)] = byte;
      }
    }
    __syncthreads();

    bf16x8 afr[6];
    #pragma unroll
    for (int kt = 0; kt < 6; ++kt){
      int row = wid*16 + colj;
      afr[kt] = *(bf16x8*)((char*)sA + row*384 + SWZ(row, kt*64 + qw*16));
    }
    f32x4 acc[8];
    #pragma unroll
    for (int nt = 0; nt < 8; ++nt) acc[nt] = (f32x4){0.f,0.f,0.f,0.f};
    #pragma unroll
    for (int nt = 0; nt < 8; ++nt){
      #pragma unroll
      for (int kt = 0; kt < 6; ++kt){
        bf16x8 bfr = *(bf16x8*)&sW[((kt*8 + nt)*64 + lane)*8];
        acc[nt] = __builtin_amdgcn_mfma_f32_16x16x32_bf16(afr[kt], bfr, acc[nt], 0,0,0);
      }
    }
    // epilogue: tanh + row l2norm (row: 16-lane group qw, reg r)
    #pragma unroll
    for (int r = 0; r < 4; ++r){
      int grow = rowbase + wid*16 + qw*4 + r;
      float t[8], ss = 0.f;
      #pragma unroll
      for (int nt = 0; nt < 8; ++nt){
        t[nt] = tanhf(acc[nt][r] + sBc[nt*16 + colj]);
        ss += t[nt]*t[nt];
      }
      ss = qreduce16(ss);
      float sc = 1.0f / fmaxf(sqrtf(ss), 1e-12f);
      #pragma unroll
      for (int nt = 0; nt < 8; ++nt){
        float v = t[nt]*sc;
        if constexpr (W16)
          e16[(size_t)grow*DD + nt*16 + colj] = (u16)bfbits(v);
        if constexpr (WF32)
          dstf[(size_t)grow*DD + nt*16 + colj] = v;
      }
    }
  }
}

// --- relation update: 64 same-layer triples/block ----------------------------
// Wave w: ALL 4 M-tiles x nt in [4w, 4w+4). Weight frag reused 4x; depth-2
// register prefetch of weight frags hides L2 latency. Cross-wave l2norm via
// sPart (subj = waves 0,1; obj = waves 2,3).
template<bool S16, bool W16, bool WF32>
__global__ __launch_bounds__(256) void k_rel(
    const float* __restrict__ ef32, u16* __restrict__ e16,
    float* __restrict__ dstf,
    const int* __restrict__ subj, const int* __restrict__ obj,
    const uint4* __restrict__ wrp, const float* __restrict__ br,
    const int* __restrict__ offs, const int* __restrict__ bins)
{
  __shared__ u16   sA[64*256];   // 32 KB pairs bf16, row stride 512 B, swizzled
  __shared__ float sBr[256];
  __shared__ float sPart[BT][4];
  __shared__ int   sS[BT], sO[BT];

  const int tid  = threadIdx.x;
  const int base = blockIdx.x * BT;
  if (base >= offs[LL]) return;
  int l = 0;
  while (l < LL-1 && base >= offs[l+1]) ++l;

  const int lane = tid & 63, wid = tid >> 6;
  const int colj = lane & 15, qw = lane >> 4;

  // issue first weight prefetches before the gather (rides under its latency)
  const uint4* wb = wrp + (size_t)l*8192 + lane;
  bf16x8 wf[8][4];
  #pragma unroll
  for (int n = 0; n < 4; ++n){
    wf[0][n] = *(const bf16x8*)&wb[(0*16 + wid*4 + n)*64];
    wf[1][n] = *(const bf16x8*)&wb[(1*16 + wid*4 + n)*64];
  }

  sBr[tid] = br[l*256 + tid];

  // gather pairs: 4 threads per triple, 128 B each
  const int ti = tid >> 2, q = tid & 3;
  int id = bins[base + ti];
  int rs = -1, ro = -1;
  if (id >= 0){ rs = subj[id]; ro = obj[id]; }
  if (q == 0){ sS[ti] = rs; sO[ti] = ro; }
  const int rr = (q < 2) ? rs : ro;
  if constexpr (S16){
    const u16* srcp = e16 + (size_t)rr*DD + (q & 1)*64;
    #pragma unroll
    for (int j = 0; j < 8; ++j){
      uint4 w = (id >= 0) ? ((const uint4*)srcp)[j] : make_uint4(0u,0u,0u,0u);
      *(uint4*)((char*)sA + ti*512 + SWZ(ti, q*128 + j*16)) = w;
    }
  } else {
    const float* srcp = ef32 + (size_t)rr*DD + (q & 1)*64;
    #pragma unroll
    for (int j = 0; j < 8; ++j){
      uint4 w;
      if (id >= 0){
        float4 a = ((const float4*)srcp)[2*j], b = ((const float4*)srcp)[2*j+1];
        w = make_uint4(pk(a.x,a.y), pk(a.z,a.w), pk(b.x,b.y), pk(b.z,b.w));
      } else w = make_uint4(0u,0u,0u,0u);
      *(uint4*)((char*)sA + ti*512 + SWZ(ti, q*128 + j*16)) = w;
    }
  }
  __syncthreads();

  f32x4 acc[4][4];
  #pragma unroll
  for (int m = 0; m < 4; ++m)
    #pragma unroll
    for (int n = 0; n < 4; ++n) acc[m][n] = (f32x4){0.f,0.f,0.f,0.f};

  #pragma unroll
  for (int kt = 0; kt < 8; ++kt){
    if (kt + 2 < 8){
      #pragma unroll
      for (int n = 0; n < 4; ++n)
        wf[kt+2][n] = *(const bf16x8*)&wb[((kt+2)*16 + wid*4 + n)*64];
    }
    #pragma unroll
    for (int m = 0; m < 4; ++m){
      int row = m*16 + colj;
      bf16x8 afr = *(bf16x8*)((char*)sA + row*512 + SWZ(row, kt*64 + qw*16));
      #pragma unroll
      for (int n = 0; n < 4; ++n)
        acc[m][n] = __builtin_amdgcn_mfma_f32_16x16x32_bf16(afr, wf[kt][n], acc[m][n], 0,0,0);
    }
  }

  // epilogue: tanh, partial norms (per wave: 4 nt = 64 cols), cross-wave sum
  #pragma unroll
  for (int m = 0; m < 4; ++m){
    #pragma unroll
    for (int n = 0; n < 4; ++n){
      float b = sBr[(wid*4 + n)*16 + colj];
      #pragma unroll
      for (int r = 0; r < 4; ++r)
        acc[m][n][r] = tanhf(acc[m][n][r] + b);
    }
    #pragma unroll
    for (int r = 0; r < 4; ++r){
      float ss = acc[m][0][r]*acc[m][0][r] + acc[m][1][r]*acc[m][1][r]
               + acc[m][2][r]*acc[m][2][r] + acc[m][3][r]*acc[m][3][r];
      ss = qreduce16(ss);
      if (colj == 0) sPart[m*16 + qw*4 + r][wid] = ss;
    }
  }
  __syncthreads();

  const int h = wid >> 1;   // 0: subj half (waves 0,1), 1: obj half (waves 2,3)
  #pragma unroll
  for (int m = 0; m < 4; ++m){
    #pragma unroll
    for (int r = 0; r < 4; ++r){
      int tri = m*16 + qw*4 + r;
      int row = h ? sO[tri] : sS[tri];
      if (row < 0) continue;
      float ss = sPart[tri][2*h] + sPart[tri][2*h + 1];
      float sc = 1.0f / fmaxf(sqrtf(ss), 1e-12f);
      #pragma unroll
      for (int n = 0; n < 4; ++n){
        int cc = (wid*4 + n)*16 + colj - h*DD;
        float v = acc[m][n][r]*sc;
        if constexpr (W16)
          e16[(size_t)row*DD + cc] = (u16)bfbits(v);
        if constexpr (WF32)
          dstf[(size_t)row*DD + cc] = v;
      }
    }
  }
}

extern "C" void kernel_launch(void* const* d_in, const int* in_sizes, int n_in,
                              void* d_out, int out_size, void* d_ws, size_t ws_size,
                              hipStream_t stream) {
  (void)in_sizes; (void)n_in; (void)out_size;
  const float* emb  = (const float*)d_in[0];
  const int*   mem  = (const int*)  d_in[1];
  const int*   subj = (const int*)  d_in[2];
  const int*   obj  = (const int*)  d_in[3];
  const int*   lay  = (const int*)  d_in[4];
  const float* Wc   = (const float*)d_in[5];
  const float* bc   = (const float*)d_in[6];
  const float* Wr   = (const float*)d_in[7];
  const float* br   = (const float*)d_in[8];

  float* e   = (float*)d_out;
  char*  wsb = (char*)d_ws;
  int*   offs  = (int*)(wsb + WS_OFFS);
  int*   cnt   = (int*)(wsb + WS_CNT);
  int*   gbase = (int*)(wsb + WS_BASE);
  int*   bins  = (int*)(wsb + WS_BINS);
  uint4* wcp   = (uint4*)(wsb + WS_WCP);
  uint4* wrp   = (uint4*)(wsb + WS_WRP);
  u64*   mbits = (u64*)(wsb + WS_MB);
  u16*   e16   = (u16*)(wsb + WS_E16);

  k_prep<<<PREPB + NB, 256, 0, stream>>>(Wc, Wr, wcp, wrp, lay, cnt);
  k_bin2<<<1, 64, 0, stream>>>(cnt, offs, gbase, bins);
  k_bin3<<<NB, 64, 0, stream>>>(lay, gbase, bins);

  if (ws_size >= WS_NEED){
    // bf16-resident e path
    k_class<false,false,true,false><<<512, 256, 0, stream>>>(
        emb, nullptr, e16, nullptr, mem, mbits, wcp, bc);
    k_rel<true,true,false><<<PADT/BT, 256, 0, stream>>>(
        nullptr, e16, nullptr, subj, obj, wrp, br, offs, bins);
    k_class<true,true,false,true><<<512, 256, 0, stream>>>(
        nullptr, e16, nullptr, e, mem, mbits, wcp, bc);
    k_rel<false,false,true><<<PADT/BT, 256, 0, stream>>>(
        e, nullptr, e, subj, obj, wrp, br, offs, bins);
  } else {
    // f32 fallback (e lives in d_out)
    k_class<false,false,false,true><<<512, 256, 0, stream>>>(
        emb, nullptr, nullptr, e, mem, mbits, wcp, bc);
    k_rel<false,false,true><<<PADT/BT, 256, 0, stream>>>(
        e, nullptr, e, subj, obj, wrp, br, offs, bins);
    k_class<false,true,false,true><<<512, 256, 0, stream>>>(
        e, nullptr, nullptr, e, mem, mbits, wcp, bc);
    k_rel<false,false,true><<<PADT/BT, 256, 0, stream>>>(
        e, nullptr, e, subj, obj, wrp, br, offs, bins);
  }
}

// Round 6
// 184.208 us; speedup vs baseline: 9.1482x; 1.1119x over previous
//
#include <hip/hip_runtime.h>
#include <hip/hip_bf16.h>

// ---------------------------------------------------------------------------
// RRN, MFMA version, parallel scan-binned, bf16-resident e.
//   iter: e = l2norm(tanh([e;mem] @ Wc + bc))            (K=192 GEMM, MFMA)
//         per triple (unique rows): out = tanh([e_s;e_o] @ Wr[l] + br[l])
//         e[s]=l2norm(out[:128]); e[o]=l2norm(out[128:])  (layer-binned MFMA)
// subj ∪ obj are distinct rows -> in-place update race-free.
// k_class: Wc B-frags live in 48 VGPRs/thread (wave w = nt{2w,2w+1} x 4 M-
// tiles) -> LDS 25.5 KB, 4 blocks/CU. Cross-wave l2norm via sPart.
// k_rel: wave w = nt[4w..4w+4) x 4 M-tiles, depth-2 L2 prefetch of W-frags.
// fast_tanh (v_exp/v_rcp) replaces library tanhf everywhere.
// ---------------------------------------------------------------------------

#define NROWS 200000
#define DD    128
#define KK    64
#define TT    50000
#define LL    8
#define BT    64
#define PADT  50560            // 64*790 >= 50000 + 8*63

#define NB    100              // binning blocks
#define CHB   500              // elements per binning block (NB*CHB == TT)
#define PL    8                // elements per lane (64*8 >= CHB)
#define PREPB 268              // weight-packing blocks in k_prep

// ws layout (bytes)
#define WS_OFFS   0
#define WS_CNT    64                        // NB*LL ints = 3200
#define WS_BASE   4096                      // NB*LL ints
#define WS_BINS   8192                      // PADT*4 = 202240
#define WS_WCP    210432                    // 48 KB, 16B aligned
#define WS_WRP    (WS_WCP + 6*8*64*16)      // 259584; 1 MB
#define WS_MB     (WS_WRP + 8*8*16*64*16)   // 1308160; 1.6 MB bit-packed mem
#define WS_E16    (WS_MB + NROWS*8)         // 2908160; 51.2 MB
#define WS_NEED   (WS_E16 + (size_t)NROWS*DD*2)

typedef unsigned short u16;
typedef unsigned int   u32;
typedef unsigned long long u64;
typedef unsigned char  u8;
typedef __attribute__((ext_vector_type(8))) short bf16x8;
typedef __attribute__((ext_vector_type(4))) float f32x4;

#define SWZ(row, byte) ((byte) ^ (((row)&7)<<4))

__device__ __forceinline__ u32 bfbits(float f){
  __hip_bfloat16 h = __float2bfloat16(f);
  return (u32)*reinterpret_cast<unsigned short*>(&h);
}
__device__ __forceinline__ u32 pk(float lo, float hi){
  return bfbits(lo) | (bfbits(hi) << 16);
}
__device__ __forceinline__ float qreduce16(float ss){
  ss += __shfl_xor(ss, 1, 64);
  ss += __shfl_xor(ss, 2, 64);
  ss += __shfl_xor(ss, 4, 64);
  ss += __shfl_xor(ss, 8, 64);
  return ss;
}
// tanh(x) = sign(x) * (1-e)/(1+e), e = exp(-2|x|).  ~10 VALU inst, rel err
// ~1e-6 (<< bf16 rounding).
__device__ __forceinline__ float fast_tanh(float x){
  float a = fabsf(x);
  float e = __expf(-2.0f*a);
  float t = (1.0f - e) * __builtin_amdgcn_rcpf(1.0f + e);
  return copysignf(t, x);
}
__device__ __forceinline__ float rnorm_scale(float ss){
  return __builtin_amdgcn_rcpf(fmaxf(__builtin_amdgcn_sqrtf(ss), 1e-12f));
}

// --- prep: pack Wc/Wr into MFMA B-frag order; extra blocks: bin counts ------
__global__ __launch_bounds__(256) void k_prep(
    const float* __restrict__ Wc, const float* __restrict__ Wr,
    uint4* __restrict__ wcp, uint4* __restrict__ wrp,
    const int* __restrict__ layer, int* __restrict__ cnt)
{
  if (blockIdx.x >= PREPB){
    const int bb = blockIdx.x - PREPB, lane = threadIdx.x;
    if (lane >= 64) return;
    const int lim = bb*CHB + CHB;
    int i0 = bb*CHB + lane*PL, i1 = i0 + PL; if (i1 > lim) i1 = lim;
    int c[LL] = {0,0,0,0,0,0,0,0};
    for (int i = i0; i < i1; ++i){
      int l = layer[i];
      #pragma unroll
      for (int k = 0; k < LL; ++k) c[k] += (l == k);
    }
    #pragma unroll
    for (int k = 0; k < LL; ++k){
      int v = c[k];
      v += __shfl_xor(v, 1, 64); v += __shfl_xor(v, 2, 64);
      v += __shfl_xor(v, 4, 64); v += __shfl_xor(v, 8, 64);
      v += __shfl_xor(v, 16, 64); v += __shfl_xor(v, 32, 64);
      if (lane == k) cnt[bb*LL + k] = v;
    }
    return;
  }
  int id = blockIdx.x*blockDim.x + threadIdx.x;
  if (id < 3072){                       // wcp: kt 0..5, nt 0..7
    int lane = id & 63, nt = (id >> 6) & 7, kt = id >> 9;
    int k0 = kt*32 + (lane>>4)*8, n = nt*16 + (lane&15);
    u32 p[4];
    #pragma unroll
    for (int e2 = 0; e2 < 4; ++e2)
      p[e2] = pk(Wc[(k0 + 2*e2)*DD + n], Wc[(k0 + 2*e2 + 1)*DD + n]);
    wcp[id] = make_uint4(p[0], p[1], p[2], p[3]);
  } else if (id < 3072 + 65536){        // wrp: l, kt 0..7, nt 0..15
    int id2 = id - 3072;
    int lane = id2 & 63, nt = (id2>>6) & 15, kt = (id2>>10) & 7, l = id2 >> 13;
    int k0 = kt*32 + (lane>>4)*8, n = nt*16 + (lane&15);
    const float* w = Wr + (size_t)l*65536;
    u32 p[4];
    #pragma unroll
    for (int e2 = 0; e2 < 4; ++e2)
      p[e2] = pk(w[(k0 + 2*e2)*256 + n], w[(k0 + 2*e2 + 1)*256 + n]);
    wrp[id2] = make_uint4(p[0], p[1], p[2], p[3]);
  }
}

// --- bin2: offsets + per-block bases + pad fill (1 tiny block) ---------------
__global__ __launch_bounds__(64) void k_bin2(const int* __restrict__ cnt,
                                             int* __restrict__ offs,
                                             int* __restrict__ gbase,
                                             int* __restrict__ bins)
{
  __shared__ int pre[NB][LL];
  __shared__ int tot[LL], soffs[LL+1];
  const int t = threadIdx.x;
  if (t < LL){
    int acc = 0;
    for (int bb = 0; bb < NB; ++bb){ pre[bb][t] = acc; acc += cnt[bb*LL + t]; }
    tot[t] = acc;
  }
  __syncthreads();
  if (t == 0){
    int acc = 0;
    for (int l = 0; l < LL; ++l){
      soffs[l] = acc; offs[l] = acc;
      acc += ((tot[l] + BT - 1)/BT)*BT;
    }
    soffs[LL] = acc; offs[LL] = acc;
  }
  __syncthreads();
  for (int idx = t; idx < NB*LL; idx += 64){
    int bb = idx >> 3, k = idx & 7;
    gbase[idx] = soffs[k] + pre[bb][k];
  }
  const int k = t >> 3, sub = t & 7;
  const int sz = soffs[k+1] - soffs[k];
  for (int i = tot[k] + sub; i < sz; i += 8) bins[soffs[k] + i] = -1;
}

// --- bin3: ordered scatter (NB one-wave blocks) -------------------------------
__global__ __launch_bounds__(64) void k_bin3(const int* __restrict__ layer,
                                             const int* __restrict__ gbase,
                                             int* __restrict__ bins)
{
  const int bb = blockIdx.x, lane = threadIdx.x;
  const int lim = bb*CHB + CHB;
  int i0 = bb*CHB + lane*PL, i1 = i0 + PL; if (i1 > lim) i1 = lim;
  int c[LL] = {0,0,0,0,0,0,0,0};
  for (int i = i0; i < i1; ++i){
    int l = layer[i];
    #pragma unroll
    for (int k = 0; k < LL; ++k) c[k] += (l == k);
  }
  int start[LL];
  #pragma unroll
  for (int k = 0; k < LL; ++k){
    int v = c[k];
    #pragma unroll
    for (int d = 1; d < 64; d <<= 1){
      int u = __shfl_up(v, d, 64);
      if (lane >= d) v += u;
    }
    start[k] = gbase[bb*LL + k] + v - c[k];
  }
  for (int i = i0; i < i1; ++i){
    int l = layer[i];
    #pragma unroll
    for (int k = 0; k < LL; ++k)
      if (l == k) bins[start[k]++] = i;
  }
}

// --- class update: dst = l2norm(tanh([src;mem] @ Wc + bc)) -------------------
// Wave w: nt in {2w, 2w+1} x all 4 M-tiles. Wc B-frags in registers (12 x
// bf16x8 = 48 VGPR). LDS: sA 24 KB + sPart + sBc -> 4 blocks/CU.
template<bool S16, bool MBITS, bool W16, bool WF32>
__global__ __launch_bounds__(256) void k_class(
    const float* __restrict__ srcf, const u16* __restrict__ src16,
    u16* __restrict__ e16, float* __restrict__ dstf,
    const int* __restrict__ mem, u64* __restrict__ mbits,
    const uint4* __restrict__ wcp, const float* __restrict__ bc)
{
  __shared__ u16   sA[64*192];     // 24 KB, row stride 384 B, XOR-swizzled
  __shared__ float sBc[DD];
  __shared__ float sPart[64][4];

  const int tid = threadIdx.x;
  const int lane = tid & 63, wid = tid >> 6;
  const int colj = lane & 15, qw = lane >> 4;

  // B-fragments for this wave's two nt tiles -> registers
  bf16x8 wf[6][2];
  #pragma unroll
  for (int kt = 0; kt < 6; ++kt)
    #pragma unroll
    for (int j = 0; j < 2; ++j)
      wf[kt][j] = *(const bf16x8*)&wcp[(kt*8 + 2*wid + j)*64 + lane];
  if (tid < DD) sBc[tid] = bc[tid];

  const float b0 = bc[(2*wid)*16 + colj];
  const float b1 = bc[(2*wid+1)*16 + colj];
  (void)sBc;

  for (int rb = blockIdx.x; rb < NROWS/64; rb += gridDim.x){
    const int rowbase = rb * 64;
    __syncthreads();   // sA/sPart reuse safe (prior pass fully read)
    // stage e-part (64x128 -> bf16 LDS)
    #pragma unroll
    for (int v = 0; v < 4; ++v){
      int f = (v*256 + tid) * 8;               // flat elem idx in 64x128
      int row = f >> 7, col = f & 127;
      uint4 out;
      if constexpr (S16){
        out = *(const uint4*)(src16 + (size_t)(rowbase+row)*DD + col);
      } else {
        const float4* s4 = (const float4*)(srcf + (size_t)(rowbase+row)*DD + col);
        float4 a = s4[0], b = s4[1];
        out = make_uint4(pk(a.x,a.y), pk(a.z,a.w), pk(b.x,b.y), pk(b.z,b.w));
      }
      *(uint4*)((char*)sA + row*384 + SWZ(row, col*2)) = out;
    }
    // stage mem-part (64x64 -> bf16 LDS)
    if constexpr (MBITS){
      const int r = tid >> 2, q = tid & 3;
      u64 m = mbits[rowbase + r];
      u32 s = (u32)(m >> (q*16)) & 0xFFFFu;
      u32 p[8];
      #pragma unroll
      for (int jj = 0; jj < 8; ++jj){
        u32 lo = (s >> (2*jj))     & 1u;
        u32 hi = (s >> (2*jj + 1)) & 1u;
        p[jj] = (lo ? 0x3F80u : 0u) | (hi ? 0x3F800000u : 0u);
      }
      *(uint4*)((char*)sA + r*384 + SWZ(r, 256 + q*32))      = make_uint4(p[0],p[1],p[2],p[3]);
      *(uint4*)((char*)sA + r*384 + SWZ(r, 256 + q*32 + 16)) = make_uint4(p[4],p[5],p[6],p[7]);
    } else {
      u8* mb8 = (u8*)mbits;
      #pragma unroll
      for (int v = 0; v < 2; ++v){
        int f = (v*256 + tid) * 8;             // flat int idx in 64x64
        int row = f >> 6, col = f & 63;
        const int4* s4 = (const int4*)(mem + (size_t)(rowbase+row)*KK + col);
        int4 a = s4[0], b = s4[1];
        u32 p0 = (a.x?0x3F80u:0u) | ((a.y?0x3F80u:0u)<<16);
        u32 p1 = (a.z?0x3F80u:0u) | ((a.w?0x3F80u:0u)<<16);
        u32 p2 = (b.x?0x3F80u:0u) | ((b.y?0x3F80u:0u)<<16);
        u32 p3 = (b.z?0x3F80u:0u) | ((b.w?0x3F80u:0u)<<16);
        *(uint4*)((char*)sA + row*384 + SWZ(row, 256 + col*2)) =
          make_uint4(p0, p1, p2, p3);
        u8 byte = (u8)((a.x!=0) | ((a.y!=0)<<1) | ((a.z!=0)<<2) | ((a.w!=0)<<3)
                 | ((b.x!=0)<<4) | ((b.y!=0)<<5) | ((b.z!=0)<<6) | ((b.w!=0)<<7));
        mb8[(size_t)(rowbase+row)*8 + (col>>3)] = byte;
      }
    }
    __syncthreads();

    f32x4 acc[4][2];
    #pragma unroll
    for (int m = 0; m < 4; ++m){
      acc[m][0] = (f32x4){0.f,0.f,0.f,0.f};
      acc[m][1] = (f32x4){0.f,0.f,0.f,0.f};
    }
    #pragma unroll
    for (int m = 0; m < 4; ++m){
      int row = m*16 + colj;
      #pragma unroll
      for (int kt = 0; kt < 6; ++kt){
        bf16x8 afr = *(bf16x8*)((char*)sA + row*384 + SWZ(row, kt*64 + qw*16));
        acc[m][0] = __builtin_amdgcn_mfma_f32_16x16x32_bf16(afr, wf[kt][0], acc[m][0], 0,0,0);
        acc[m][1] = __builtin_amdgcn_mfma_f32_16x16x32_bf16(afr, wf[kt][1], acc[m][1], 0,0,0);
      }
    }
    // epilogue: fast_tanh + cross-wave l2norm via sPart
    #pragma unroll
    for (int m = 0; m < 4; ++m){
      #pragma unroll
      for (int r = 0; r < 4; ++r){
        float t0 = fast_tanh(acc[m][0][r] + b0);
        float t1 = fast_tanh(acc[m][1][r] + b1);
        acc[m][0][r] = t0; acc[m][1][r] = t1;
        float ss = qreduce16(t0*t0 + t1*t1);
        if (colj == 0) sPart[m*16 + qw*4 + r][wid] = ss;
      }
    }
    __syncthreads();
    #pragma unroll
    for (int m = 0; m < 4; ++m){
      #pragma unroll
      for (int r = 0; r < 4; ++r){
        int tri = m*16 + qw*4 + r;
        f32x4 p = *(f32x4*)sPart[tri];
        float sc = rnorm_scale(p[0] + p[1] + p[2] + p[3]);
        int grow = rowbase + tri;
        float v0 = acc[m][0][r]*sc, v1 = acc[m][1][r]*sc;
        int c0 = (2*wid)*16 + colj;
        if constexpr (W16){
          e16[(size_t)grow*DD + c0]      = (u16)bfbits(v0);
          e16[(size_t)grow*DD + c0 + 16] = (u16)bfbits(v1);
        }
        if constexpr (WF32){
          dstf[(size_t)grow*DD + c0]      = v0;
          dstf[(size_t)grow*DD + c0 + 16] = v1;
        }
      }
    }
  }
}

// --- relation update: 64 same-layer triples/block ----------------------------
// Wave w: ALL 4 M-tiles x nt in [4w, 4w+4). Weight frag reused 4x; depth-2
// register prefetch of weight frags hides L2 latency. Cross-wave l2norm via
// sPart (subj = waves 0,1; obj = waves 2,3).
template<bool S16, bool W16, bool WF32>
__global__ __launch_bounds__(256) void k_rel(
    const float* __restrict__ ef32, u16* __restrict__ e16,
    float* __restrict__ dstf,
    const int* __restrict__ subj, const int* __restrict__ obj,
    const uint4* __restrict__ wrp, const float* __restrict__ br,
    const int* __restrict__ offs, const int* __restrict__ bins)
{
  __shared__ u16   sA[64*256];   // 32 KB pairs bf16, row stride 512 B, swizzled
  __shared__ float sBr[256];
  __shared__ float sPart[BT][4];
  __shared__ int   sS[BT], sO[BT];

  const int tid  = threadIdx.x;
  const int base = blockIdx.x * BT;
  if (base >= offs[LL]) return;
  int l = 0;
  while (l < LL-1 && base >= offs[l+1]) ++l;

  const int lane = tid & 63, wid = tid >> 6;
  const int colj = lane & 15, qw = lane >> 4;

  // issue first weight prefetches before the gather (rides under its latency)
  const uint4* wb = wrp + (size_t)l*8192 + lane;
  bf16x8 wf[8][4];
  #pragma unroll
  for (int n = 0; n < 4; ++n){
    wf[0][n] = *(const bf16x8*)&wb[(0*16 + wid*4 + n)*64];
    wf[1][n] = *(const bf16x8*)&wb[(1*16 + wid*4 + n)*64];
  }

  sBr[tid] = br[l*256 + tid];

  // gather pairs: 4 threads per triple, 128 B each
  const int ti = tid >> 2, q = tid & 3;
  int id = bins[base + ti];
  int rs = -1, ro = -1;
  if (id >= 0){ rs = subj[id]; ro = obj[id]; }
  if (q == 0){ sS[ti] = rs; sO[ti] = ro; }
  const int rr = (q < 2) ? rs : ro;
  if constexpr (S16){
    const u16* srcp = e16 + (size_t)rr*DD + (q & 1)*64;
    #pragma unroll
    for (int j = 0; j < 8; ++j){
      uint4 w = (id >= 0) ? ((const uint4*)srcp)[j] : make_uint4(0u,0u,0u,0u);
      *(uint4*)((char*)sA + ti*512 + SWZ(ti, q*128 + j*16)) = w;
    }
  } else {
    const float* srcp = ef32 + (size_t)rr*DD + (q & 1)*64;
    #pragma unroll
    for (int j = 0; j < 8; ++j){
      uint4 w;
      if (id >= 0){
        float4 a = ((const float4*)srcp)[2*j], b = ((const float4*)srcp)[2*j+1];
        w = make_uint4(pk(a.x,a.y), pk(a.z,a.w), pk(b.x,b.y), pk(b.z,b.w));
      } else w = make_uint4(0u,0u,0u,0u);
      *(uint4*)((char*)sA + ti*512 + SWZ(ti, q*128 + j*16)) = w;
    }
  }
  __syncthreads();

  f32x4 acc[4][4];
  #pragma unroll
  for (int m = 0; m < 4; ++m)
    #pragma unroll
    for (int n = 0; n < 4; ++n) acc[m][n] = (f32x4){0.f,0.f,0.f,0.f};

  #pragma unroll
  for (int kt = 0; kt < 8; ++kt){
    if (kt + 2 < 8){
      #pragma unroll
      for (int n = 0; n < 4; ++n)
        wf[kt+2][n] = *(const bf16x8*)&wb[((kt+2)*16 + wid*4 + n)*64];
    }
    #pragma unroll
    for (int m = 0; m < 4; ++m){
      int row = m*16 + colj;
      bf16x8 afr = *(bf16x8*)((char*)sA + row*512 + SWZ(row, kt*64 + qw*16));
      #pragma unroll
      for (int n = 0; n < 4; ++n)
        acc[m][n] = __builtin_amdgcn_mfma_f32_16x16x32_bf16(afr, wf[kt][n], acc[m][n], 0,0,0);
    }
  }

  // epilogue: tanh, partial norms (per wave: 4 nt = 64 cols), cross-wave sum
  #pragma unroll
  for (int m = 0; m < 4; ++m){
    #pragma unroll
    for (int n = 0; n < 4; ++n){
      float b = sBr[(wid*4 + n)*16 + colj];
      #pragma unroll
      for (int r = 0; r < 4; ++r)
        acc[m][n][r] = fast_tanh(acc[m][n][r] + b);
    }
    #pragma unroll
    for (int r = 0; r < 4; ++r){
      float ss = acc[m][0][r]*acc[m][0][r] + acc[m][1][r]*acc[m][1][r]
               + acc[m][2][r]*acc[m][2][r] + acc[m][3][r]*acc[m][3][r];
      ss = qreduce16(ss);
      if (colj == 0) sPart[m*16 + qw*4 + r][wid] = ss;
    }
  }
  __syncthreads();

  const int h = wid >> 1;   // 0: subj half (waves 0,1), 1: obj half (waves 2,3)
  #pragma unroll
  for (int m = 0; m < 4; ++m){
    #pragma unroll
    for (int r = 0; r < 4; ++r){
      int tri = m*16 + qw*4 + r;
      int row = h ? sO[tri] : sS[tri];
      if (row < 0) continue;
      float ss = sPart[tri][2*h] + sPart[tri][2*h + 1];
      float sc = rnorm_scale(ss);
      #pragma unroll
      for (int n = 0; n < 4; ++n){
        int cc = (wid*4 + n)*16 + colj - h*DD;
        float v = acc[m][n][r]*sc;
        if constexpr (W16)
          e16[(size_t)row*DD + cc] = (u16)bfbits(v);
        if constexpr (WF32)
          dstf[(size_t)row*DD + cc] = v;
      }
    }
  }
}

extern "C" void kernel_launch(void* const* d_in, const int* in_sizes, int n_in,
                              void* d_out, int out_size, void* d_ws, size_t ws_size,
                              hipStream_t stream) {
  (void)in_sizes; (void)n_in; (void)out_size;
  const float* emb  = (const float*)d_in[0];
  const int*   mem  = (const int*)  d_in[1];
  const int*   subj = (const int*)  d_in[2];
  const int*   obj  = (const int*)  d_in[3];
  const int*   lay  = (const int*)  d_in[4];
  const float* Wc   = (const float*)d_in[5];
  const float* bc   = (const float*)d_in[6];
  const float* Wr   = (const float*)d_in[7];
  const float* br   = (const float*)d_in[8];

  float* e   = (float*)d_out;
  char*  wsb = (char*)d_ws;
  int*   offs  = (int*)(wsb + WS_OFFS);
  int*   cnt   = (int*)(wsb + WS_CNT);
  int*   gbase = (int*)(wsb + WS_BASE);
  int*   bins  = (int*)(wsb + WS_BINS);
  uint4* wcp   = (uint4*)(wsb + WS_WCP);
  uint4* wrp   = (uint4*)(wsb + WS_WRP);
  u64*   mbits = (u64*)(wsb + WS_MB);
  u16*   e16   = (u16*)(wsb + WS_E16);

  k_prep<<<PREPB + NB, 256, 0, stream>>>(Wc, Wr, wcp, wrp, lay, cnt);
  k_bin2<<<1, 64, 0, stream>>>(cnt, offs, gbase, bins);
  k_bin3<<<NB, 64, 0, stream>>>(lay, gbase, bins);

  if (ws_size >= WS_NEED){
    // bf16-resident e path
    k_class<false,false,true,false><<<1024, 256, 0, stream>>>(
        emb, nullptr, e16, nullptr, mem, mbits, wcp, bc);
    k_rel<true,true,false><<<PADT/BT, 256, 0, stream>>>(
        nullptr, e16, nullptr, subj, obj, wrp, br, offs, bins);
    k_class<true,true,false,true><<<1024, 256, 0, stream>>>(
        nullptr, e16, nullptr, e, mem, mbits, wcp, bc);
    k_rel<false,false,true><<<PADT/BT, 256, 0, stream>>>(
        e, nullptr, e, subj, obj, wrp, br, offs, bins);
  } else {
    // f32 fallback (e lives in d_out)
    k_class<false,false,false,true><<<1024, 256, 0, stream>>>(
        emb, nullptr, nullptr, e, mem, mbits, wcp, bc);
    k_rel<false,false,true><<<PADT/BT, 256, 0, stream>>>(
        e, nullptr, e, subj, obj, wrp, br, offs, bins);
    k_class<false,true,false,true><<<1024, 256, 0, stream>>>(
        e, nullptr, nullptr, e, mem, mbits, wcp, bc);
    k_rel<false,false,true><<<PADT/BT, 256, 0, stream>>>(
        e, nullptr, e, subj, obj, wrp, br, offs, bins);
  }
}

// Round 7
// 166.567 us; speedup vs baseline: 10.1171x; 1.1059x over previous
//
#include <hip/hip_runtime.h>
#include <hip/hip_bf16.h>

// ---------------------------------------------------------------------------
// RRN, MFMA version, parallel scan-binned, bf16-resident e.
//   iter: e = l2norm(tanh([e;mem] @ Wc + bc))            (K=192 GEMM, MFMA)
//         per triple (unique rows): out = tanh([e_s;e_o] @ Wr[l] + br[l])
//         e[s]=l2norm(out[:128]); e[o]=l2norm(out[128:])  (layer-binned MFMA)
// subj ∪ obj are distinct rows -> in-place update race-free.
// k_class: ONE 64-row pass per block (grid 3125, no stride loop) -> blocks at
// independent phases hide HBM latency; staging loads issued at entry (T14).
// Wc B-frags in 48 VGPRs/thread (wave w = nt{2w,2w+1} x 4 M-tiles).
// k_rel: wave w = nt[4w..4w+4) x 4 M-tiles, depth-2 L2 prefetch of W-frags.
// fast_tanh (v_exp/v_rcp) replaces library tanhf everywhere.
// ---------------------------------------------------------------------------

#define NROWS 200000
#define DD    128
#define KK    64
#define TT    50000
#define LL    8
#define BT    64
#define PADT  50560            // 64*790 >= 50000 + 8*63

#define NB    100              // binning blocks
#define CHB   500              // elements per binning block (NB*CHB == TT)
#define PL    8                // elements per lane (64*8 >= CHB)
#define PREPB 268              // weight-packing blocks in k_prep

// ws layout (bytes)
#define WS_OFFS   0
#define WS_CNT    64                        // NB*LL ints = 3200
#define WS_BASE   4096                      // NB*LL ints
#define WS_BINS   8192                      // PADT*4 = 202240
#define WS_WCP    210432                    // 48 KB, 16B aligned
#define WS_WRP    (WS_WCP + 6*8*64*16)      // 259584; 1 MB
#define WS_MB     (WS_WRP + 8*8*16*64*16)   // 1308160; 1.6 MB bit-packed mem
#define WS_E16    (WS_MB + NROWS*8)         // 2908160; 51.2 MB
#define WS_NEED   (WS_E16 + (size_t)NROWS*DD*2)

typedef unsigned short u16;
typedef unsigned int   u32;
typedef unsigned long long u64;
typedef unsigned char  u8;
typedef __attribute__((ext_vector_type(8))) short bf16x8;
typedef __attribute__((ext_vector_type(4))) float f32x4;

#define SWZ(row, byte) ((byte) ^ (((row)&7)<<4))

__device__ __forceinline__ u32 bfbits(float f){
  __hip_bfloat16 h = __float2bfloat16(f);
  return (u32)*reinterpret_cast<unsigned short*>(&h);
}
__device__ __forceinline__ u32 pk(float lo, float hi){
  return bfbits(lo) | (bfbits(hi) << 16);
}
__device__ __forceinline__ float qreduce16(float ss){
  ss += __shfl_xor(ss, 1, 64);
  ss += __shfl_xor(ss, 2, 64);
  ss += __shfl_xor(ss, 4, 64);
  ss += __shfl_xor(ss, 8, 64);
  return ss;
}
// tanh(x) = sign(x) * (1-e)/(1+e), e = exp(-2|x|).  ~10 VALU inst, rel err
// ~1e-6 (<< bf16 rounding).
__device__ __forceinline__ float fast_tanh(float x){
  float a = fabsf(x);
  float e = __expf(-2.0f*a);
  float t = (1.0f - e) * __builtin_amdgcn_rcpf(1.0f + e);
  return copysignf(t, x);
}
__device__ __forceinline__ float rnorm_scale(float ss){
  return __builtin_amdgcn_rcpf(fmaxf(__builtin_amdgcn_sqrtf(ss), 1e-12f));
}

// --- prep: pack Wc/Wr into MFMA B-frag order; extra blocks: bin counts ------
__global__ __launch_bounds__(256) void k_prep(
    const float* __restrict__ Wc, const float* __restrict__ Wr,
    uint4* __restrict__ wcp, uint4* __restrict__ wrp,
    const int* __restrict__ layer, int* __restrict__ cnt)
{
  if (blockIdx.x >= PREPB){
    const int bb = blockIdx.x - PREPB, lane = threadIdx.x;
    if (lane >= 64) return;
    const int lim = bb*CHB + CHB;
    int i0 = bb*CHB + lane*PL, i1 = i0 + PL; if (i1 > lim) i1 = lim;
    int c[LL] = {0,0,0,0,0,0,0,0};
    for (int i = i0; i < i1; ++i){
      int l = layer[i];
      #pragma unroll
      for (int k = 0; k < LL; ++k) c[k] += (l == k);
    }
    #pragma unroll
    for (int k = 0; k < LL; ++k){
      int v = c[k];
      v += __shfl_xor(v, 1, 64); v += __shfl_xor(v, 2, 64);
      v += __shfl_xor(v, 4, 64); v += __shfl_xor(v, 8, 64);
      v += __shfl_xor(v, 16, 64); v += __shfl_xor(v, 32, 64);
      if (lane == k) cnt[bb*LL + k] = v;
    }
    return;
  }
  int id = blockIdx.x*blockDim.x + threadIdx.x;
  if (id < 3072){                       // wcp: kt 0..5, nt 0..7
    int lane = id & 63, nt = (id >> 6) & 7, kt = id >> 9;
    int k0 = kt*32 + (lane>>4)*8, n = nt*16 + (lane&15);
    u32 p[4];
    #pragma unroll
    for (int e2 = 0; e2 < 4; ++e2)
      p[e2] = pk(Wc[(k0 + 2*e2)*DD + n], Wc[(k0 + 2*e2 + 1)*DD + n]);
    wcp[id] = make_uint4(p[0], p[1], p[2], p[3]);
  } else if (id < 3072 + 65536){        // wrp: l, kt 0..7, nt 0..15
    int id2 = id - 3072;
    int lane = id2 & 63, nt = (id2>>6) & 15, kt = (id2>>10) & 7, l = id2 >> 13;
    int k0 = kt*32 + (lane>>4)*8, n = nt*16 + (lane&15);
    const float* w = Wr + (size_t)l*65536;
    u32 p[4];
    #pragma unroll
    for (int e2 = 0; e2 < 4; ++e2)
      p[e2] = pk(w[(k0 + 2*e2)*256 + n], w[(k0 + 2*e2 + 1)*256 + n]);
    wrp[id2] = make_uint4(p[0], p[1], p[2], p[3]);
  }
}

// --- bin2: offsets + per-block bases + pad fill (1 tiny block) ---------------
__global__ __launch_bounds__(64) void k_bin2(const int* __restrict__ cnt,
                                             int* __restrict__ offs,
                                             int* __restrict__ gbase,
                                             int* __restrict__ bins)
{
  __shared__ int pre[NB][LL];
  __shared__ int tot[LL], soffs[LL+1];
  const int t = threadIdx.x;
  if (t < LL){
    int acc = 0;
    for (int bb = 0; bb < NB; ++bb){ pre[bb][t] = acc; acc += cnt[bb*LL + t]; }
    tot[t] = acc;
  }
  __syncthreads();
  if (t == 0){
    int acc = 0;
    for (int l = 0; l < LL; ++l){
      soffs[l] = acc; offs[l] = acc;
      acc += ((tot[l] + BT - 1)/BT)*BT;
    }
    soffs[LL] = acc; offs[LL] = acc;
  }
  __syncthreads();
  for (int idx = t; idx < NB*LL; idx += 64){
    int bb = idx >> 3, k = idx & 7;
    gbase[idx] = soffs[k] + pre[bb][k];
  }
  const int k = t >> 3, sub = t & 7;
  const int sz = soffs[k+1] - soffs[k];
  for (int i = tot[k] + sub; i < sz; i += 8) bins[soffs[k] + i] = -1;
}

// --- bin3: ordered scatter (NB one-wave blocks) -------------------------------
__global__ __launch_bounds__(64) void k_bin3(const int* __restrict__ layer,
                                             const int* __restrict__ gbase,
                                             int* __restrict__ bins)
{
  const int bb = blockIdx.x, lane = threadIdx.x;
  const int lim = bb*CHB + CHB;
  int i0 = bb*CHB + lane*PL, i1 = i0 + PL; if (i1 > lim) i1 = lim;
  int c[LL] = {0,0,0,0,0,0,0,0};
  for (int i = i0; i < i1; ++i){
    int l = layer[i];
    #pragma unroll
    for (int k = 0; k < LL; ++k) c[k] += (l == k);
  }
  int start[LL];
  #pragma unroll
  for (int k = 0; k < LL; ++k){
    int v = c[k];
    #pragma unroll
    for (int d = 1; d < 64; d <<= 1){
      int u = __shfl_up(v, d, 64);
      if (lane >= d) v += u;
    }
    start[k] = gbase[bb*LL + k] + v - c[k];
  }
  for (int i = i0; i < i1; ++i){
    int l = layer[i];
    #pragma unroll
    for (int k = 0; k < LL; ++k)
      if (l == k) bins[start[k]++] = i;
  }
}

// --- class update: dst = l2norm(tanh([src;mem] @ Wc + bc)) -------------------
// ONE 64-row pass per block. Staging global loads issued at entry (before the
// wf L2 loads) so HBM latency hides under them. Wave w: nt {2w,2w+1} x 4 M-
// tiles; Wc B-frags in registers. Cross-wave l2norm via sPart.
template<bool S16, bool MBITS, bool W16, bool WF32>
__global__ __launch_bounds__(256) void k_class(
    const float* __restrict__ srcf, const u16* __restrict__ src16,
    u16* __restrict__ e16, float* __restrict__ dstf,
    const int* __restrict__ mem, u64* __restrict__ mbits,
    const uint4* __restrict__ wcp, const float* __restrict__ bc)
{
  __shared__ u16   sA[64*192];     // 24 KB, row stride 384 B, XOR-swizzled
  __shared__ float sPart[64][4];

  const int tid = threadIdx.x;
  const int lane = tid & 63, wid = tid >> 6;
  const int colj = lane & 15, qw = lane >> 4;
  const int rowbase = blockIdx.x * 64;

  // --- 1) issue ALL staging global loads into registers first (T14) ---------
  int erow[4], ecol[4];
  uint4  eA[4];          // S16 path payload
  float4 fA[4][2];       // f32 path payload
  #pragma unroll
  for (int v = 0; v < 4; ++v){
    int f = (v*256 + tid) * 8;               // flat elem idx in 64x128
    erow[v] = f >> 7; ecol[v] = f & 127;
    if constexpr (S16){
      eA[v] = *(const uint4*)(src16 + (size_t)(rowbase+erow[v])*DD + ecol[v]);
    } else {
      const float4* s4 = (const float4*)(srcf + (size_t)(rowbase+erow[v])*DD + ecol[v]);
      fA[v][0] = s4[0]; fA[v][1] = s4[1];
    }
  }
  u64 mv = 0;
  int4 mA[2][2]; int mrow[2], mcol[2];
  if constexpr (MBITS){
    mv = mbits[rowbase + (tid >> 2)];
  } else {
    #pragma unroll
    for (int v = 0; v < 2; ++v){
      int f = (v*256 + tid) * 8;             // flat int idx in 64x64
      mrow[v] = f >> 6; mcol[v] = f & 63;
      const int4* s4 = (const int4*)(mem + (size_t)(rowbase+mrow[v])*KK + mcol[v]);
      mA[v][0] = s4[0]; mA[v][1] = s4[1];
    }
  }

  // --- 2) Wc B-fragments (L2-resident) -> registers --------------------------
  bf16x8 wf[6][2];
  #pragma unroll
  for (int kt = 0; kt < 6; ++kt)
    #pragma unroll
    for (int j = 0; j < 2; ++j)
      wf[kt][j] = *(const bf16x8*)&wcp[(kt*8 + 2*wid + j)*64 + lane];
  const float b0 = bc[(2*wid)*16 + colj];
  const float b1 = bc[(2*wid+1)*16 + colj];

  // --- 3) LDS writes ---------------------------------------------------------
  #pragma unroll
  for (int v = 0; v < 4; ++v){
    uint4 out;
    if constexpr (S16){
      out = eA[v];
    } else {
      float4 a = fA[v][0], b = fA[v][1];
      out = make_uint4(pk(a.x,a.y), pk(a.z,a.w), pk(b.x,b.y), pk(b.z,b.w));
    }
    *(uint4*)((char*)sA + erow[v]*384 + SWZ(erow[v], ecol[v]*2)) = out;
  }
  if constexpr (MBITS){
    const int r = tid >> 2, q = tid & 3;
    u32 s = (u32)(mv >> (q*16)) & 0xFFFFu;
    u32 p[8];
    #pragma unroll
    for (int jj = 0; jj < 8; ++jj){
      u32 lo = (s >> (2*jj))     & 1u;
      u32 hi = (s >> (2*jj + 1)) & 1u;
      p[jj] = (lo ? 0x3F80u : 0u) | (hi ? 0x3F800000u : 0u);
    }
    *(uint4*)((char*)sA + r*384 + SWZ(r, 256 + q*32))      = make_uint4(p[0],p[1],p[2],p[3]);
    *(uint4*)((char*)sA + r*384 + SWZ(r, 256 + q*32 + 16)) = make_uint4(p[4],p[5],p[6],p[7]);
  } else {
    u8* mb8 = (u8*)mbits;
    #pragma unroll
    for (int v = 0; v < 2; ++v){
      int4 a = mA[v][0], b = mA[v][1];
      u32 p0 = (a.x?0x3F80u:0u) | ((a.y?0x3F80u:0u)<<16);
      u32 p1 = (a.z?0x3F80u:0u) | ((a.w?0x3F80u:0u)<<16);
      u32 p2 = (b.x?0x3F80u:0u) | ((b.y?0x3F80u:0u)<<16);
      u32 p3 = (b.z?0x3F80u:0u) | ((b.w?0x3F80u:0u)<<16);
      *(uint4*)((char*)sA + mrow[v]*384 + SWZ(mrow[v], 256 + mcol[v]*2)) =
        make_uint4(p0, p1, p2, p3);
      u8 byte = (u8)((a.x!=0) | ((a.y!=0)<<1) | ((a.z!=0)<<2) | ((a.w!=0)<<3)
               | ((b.x!=0)<<4) | ((b.y!=0)<<5) | ((b.z!=0)<<6) | ((b.w!=0)<<7));
      mb8[(size_t)(rowbase+mrow[v])*8 + (mcol[v]>>3)] = byte;
    }
  }
  __syncthreads();

  // --- 4) MFMA ---------------------------------------------------------------
  f32x4 acc[4][2];
  #pragma unroll
  for (int m = 0; m < 4; ++m){
    acc[m][0] = (f32x4){0.f,0.f,0.f,0.f};
    acc[m][1] = (f32x4){0.f,0.f,0.f,0.f};
  }
  #pragma unroll
  for (int m = 0; m < 4; ++m){
    int row = m*16 + colj;
    #pragma unroll
    for (int kt = 0; kt < 6; ++kt){
      bf16x8 afr = *(bf16x8*)((char*)sA + row*384 + SWZ(row, kt*64 + qw*16));
      acc[m][0] = __builtin_amdgcn_mfma_f32_16x16x32_bf16(afr, wf[kt][0], acc[m][0], 0,0,0);
      acc[m][1] = __builtin_amdgcn_mfma_f32_16x16x32_bf16(afr, wf[kt][1], acc[m][1], 0,0,0);
    }
  }
  // --- 5) epilogue: fast_tanh + cross-wave l2norm via sPart ------------------
  #pragma unroll
  for (int m = 0; m < 4; ++m){
    #pragma unroll
    for (int r = 0; r < 4; ++r){
      float t0 = fast_tanh(acc[m][0][r] + b0);
      float t1 = fast_tanh(acc[m][1][r] + b1);
      acc[m][0][r] = t0; acc[m][1][r] = t1;
      float ss = qreduce16(t0*t0 + t1*t1);
      if (colj == 0) sPart[m*16 + qw*4 + r][wid] = ss;
    }
  }
  __syncthreads();
  #pragma unroll
  for (int m = 0; m < 4; ++m){
    #pragma unroll
    for (int r = 0; r < 4; ++r){
      int tri = m*16 + qw*4 + r;
      f32x4 p = *(f32x4*)sPart[tri];
      float sc = rnorm_scale(p[0] + p[1] + p[2] + p[3]);
      int grow = rowbase + tri;
      float v0 = acc[m][0][r]*sc, v1 = acc[m][1][r]*sc;
      int c0 = (2*wid)*16 + colj;
      if constexpr (W16){
        e16[(size_t)grow*DD + c0]      = (u16)bfbits(v0);
        e16[(size_t)grow*DD + c0 + 16] = (u16)bfbits(v1);
      }
      if constexpr (WF32){
        dstf[(size_t)grow*DD + c0]      = v0;
        dstf[(size_t)grow*DD + c0 + 16] = v1;
      }
    }
  }
}

// --- relation update: 64 same-layer triples/block ----------------------------
// Wave w: ALL 4 M-tiles x nt in [4w, 4w+4). Weight frag reused 4x; depth-2
// register prefetch of weight frags hides L2 latency. Cross-wave l2norm via
// sPart (subj = waves 0,1; obj = waves 2,3).
template<bool S16, bool W16, bool WF32>
__global__ __launch_bounds__(256) void k_rel(
    const float* __restrict__ ef32, u16* __restrict__ e16,
    float* __restrict__ dstf,
    const int* __restrict__ subj, const int* __restrict__ obj,
    const uint4* __restrict__ wrp, const float* __restrict__ br,
    const int* __restrict__ offs, const int* __restrict__ bins)
{
  __shared__ u16   sA[64*256];   // 32 KB pairs bf16, row stride 512 B, swizzled
  __shared__ float sBr[256];
  __shared__ float sPart[BT][4];
  __shared__ int   sS[BT], sO[BT];

  const int tid  = threadIdx.x;
  const int base = blockIdx.x * BT;
  if (base >= offs[LL]) return;
  int l = 0;
  while (l < LL-1 && base >= offs[l+1]) ++l;

  const int lane = tid & 63, wid = tid >> 6;
  const int colj = lane & 15, qw = lane >> 4;

  // issue first weight prefetches before the gather (rides under its latency)
  const uint4* wb = wrp + (size_t)l*8192 + lane;
  bf16x8 wf[8][4];
  #pragma unroll
  for (int n = 0; n < 4; ++n){
    wf[0][n] = *(const bf16x8*)&wb[(0*16 + wid*4 + n)*64];
    wf[1][n] = *(const bf16x8*)&wb[(1*16 + wid*4 + n)*64];
  }

  sBr[tid] = br[l*256 + tid];

  // gather pairs: 4 threads per triple, 128 B each
  const int ti = tid >> 2, q = tid & 3;
  int id = bins[base + ti];
  int rs = -1, ro = -1;
  if (id >= 0){ rs = subj[id]; ro = obj[id]; }
  if (q == 0){ sS[ti] = rs; sO[ti] = ro; }
  const int rr = (q < 2) ? rs : ro;
  if constexpr (S16){
    const u16* srcp = e16 + (size_t)rr*DD + (q & 1)*64;
    #pragma unroll
    for (int j = 0; j < 8; ++j){
      uint4 w = (id >= 0) ? ((const uint4*)srcp)[j] : make_uint4(0u,0u,0u,0u);
      *(uint4*)((char*)sA + ti*512 + SWZ(ti, q*128 + j*16)) = w;
    }
  } else {
    const float* srcp = ef32 + (size_t)rr*DD + (q & 1)*64;
    #pragma unroll
    for (int j = 0; j < 8; ++j){
      uint4 w;
      if (id >= 0){
        float4 a = ((const float4*)srcp)[2*j], b = ((const float4*)srcp)[2*j+1];
        w = make_uint4(pk(a.x,a.y), pk(a.z,a.w), pk(b.x,b.y), pk(b.z,b.w));
      } else w = make_uint4(0u,0u,0u,0u);
      *(uint4*)((char*)sA + ti*512 + SWZ(ti, q*128 + j*16)) = w;
    }
  }
  __syncthreads();

  f32x4 acc[4][4];
  #pragma unroll
  for (int m = 0; m < 4; ++m)
    #pragma unroll
    for (int n = 0; n < 4; ++n) acc[m][n] = (f32x4){0.f,0.f,0.f,0.f};

  #pragma unroll
  for (int kt = 0; kt < 8; ++kt){
    if (kt + 2 < 8){
      #pragma unroll
      for (int n = 0; n < 4; ++n)
        wf[kt+2][n] = *(const bf16x8*)&wb[((kt+2)*16 + wid*4 + n)*64];
    }
    #pragma unroll
    for (int m = 0; m < 4; ++m){
      int row = m*16 + colj;
      bf16x8 afr = *(bf16x8*)((char*)sA + row*512 + SWZ(row, kt*64 + qw*16));
      #pragma unroll
      for (int n = 0; n < 4; ++n)
        acc[m][n] = __builtin_amdgcn_mfma_f32_16x16x32_bf16(afr, wf[kt][n], acc[m][n], 0,0,0);
    }
  }

  // epilogue: tanh, partial norms (per wave: 4 nt = 64 cols), cross-wave sum
  #pragma unroll
  for (int m = 0; m < 4; ++m){
    #pragma unroll
    for (int n = 0; n < 4; ++n){
      float b = sBr[(wid*4 + n)*16 + colj];
      #pragma unroll
      for (int r = 0; r < 4; ++r)
        acc[m][n][r] = fast_tanh(acc[m][n][r] + b);
    }
    #pragma unroll
    for (int r = 0; r < 4; ++r){
      float ss = acc[m][0][r]*acc[m][0][r] + acc[m][1][r]*acc[m][1][r]
               + acc[m][2][r]*acc[m][2][r] + acc[m][3][r]*acc[m][3][r];
      ss = qreduce16(ss);
      if (colj == 0) sPart[m*16 + qw*4 + r][wid] = ss;
    }
  }
  __syncthreads();

  const int h = wid >> 1;   // 0: subj half (waves 0,1), 1: obj half (waves 2,3)
  #pragma unroll
  for (int m = 0; m < 4; ++m){
    #pragma unroll
    for (int r = 0; r < 4; ++r){
      int tri = m*16 + qw*4 + r;
      int row = h ? sO[tri] : sS[tri];
      if (row < 0) continue;
      float ss = sPart[tri][2*h] + sPart[tri][2*h + 1];
      float sc = rnorm_scale(ss);
      #pragma unroll
      for (int n = 0; n < 4; ++n){
        int cc = (wid*4 + n)*16 + colj - h*DD;
        float v = acc[m][n][r]*sc;
        if constexpr (W16)
          e16[(size_t)row*DD + cc] = (u16)bfbits(v);
        if constexpr (WF32)
          dstf[(size_t)row*DD + cc] = v;
      }
    }
  }
}

extern "C" void kernel_launch(void* const* d_in, const int* in_sizes, int n_in,
                              void* d_out, int out_size, void* d_ws, size_t ws_size,
                              hipStream_t stream) {
  (void)in_sizes; (void)n_in; (void)out_size;
  const float* emb  = (const float*)d_in[0];
  const int*   mem  = (const int*)  d_in[1];
  const int*   subj = (const int*)  d_in[2];
  const int*   obj  = (const int*)  d_in[3];
  const int*   lay  = (const int*)  d_in[4];
  const float* Wc   = (const float*)d_in[5];
  const float* bc   = (const float*)d_in[6];
  const float* Wr   = (const float*)d_in[7];
  const float* br   = (const float*)d_in[8];

  float* e   = (float*)d_out;
  char*  wsb = (char*)d_ws;
  int*   offs  = (int*)(wsb + WS_OFFS);
  int*   cnt   = (int*)(wsb + WS_CNT);
  int*   gbase = (int*)(wsb + WS_BASE);
  int*   bins  = (int*)(wsb + WS_BINS);
  uint4* wcp   = (uint4*)(wsb + WS_WCP);
  uint4* wrp   = (uint4*)(wsb + WS_WRP);
  u64*   mbits = (u64*)(wsb + WS_MB);
  u16*   e16   = (u16*)(wsb + WS_E16);

  k_prep<<<PREPB + NB, 256, 0, stream>>>(Wc, Wr, wcp, wrp, lay, cnt);
  k_bin2<<<1, 64, 0, stream>>>(cnt, offs, gbase, bins);
  k_bin3<<<NB, 64, 0, stream>>>(lay, gbase, bins);

  const int GC = NROWS/64;   // 3125 one-pass blocks
  if (ws_size >= WS_NEED){
    // bf16-resident e path
    k_class<false,false,true,false><<<GC, 256, 0, stream>>>(
        emb, nullptr, e16, nullptr, mem, mbits, wcp, bc);
    k_rel<true,true,false><<<PADT/BT, 256, 0, stream>>>(
        nullptr, e16, nullptr, subj, obj, wrp, br, offs, bins);
    k_class<true,true,false,true><<<GC, 256, 0, stream>>>(
        nullptr, e16, nullptr, e, mem, mbits, wcp, bc);
    k_rel<false,false,true><<<PADT/BT, 256, 0, stream>>>(
        e, nullptr, e, subj, obj, wrp, br, offs, bins);
  } else {
    // f32 fallback (e lives in d_out)
    k_class<false,false,false,true><<<GC, 256, 0, stream>>>(
        emb, nullptr, nullptr, e, mem, mbits, wcp, bc);
    k_rel<false,false,true><<<PADT/BT, 256, 0, stream>>>(
        e, nullptr, e, subj, obj, wrp, br, offs, bins);
    k_class<false,true,false,true><<<GC, 256, 0, stream>>>(
        e, nullptr, nullptr, e, mem, mbits, wcp, bc);
    k_rel<false,false,true><<<PADT/BT, 256, 0, stream>>>(
        e, nullptr, e, subj, obj, wrp, br, offs, bins);
  }
}